// Round 9
// baseline (449.626 us; speedup 1.0000x reference)
//
#include <hip/hip_runtime.h>
#include <hip/hip_bf16.h>

#define N_NODES 50000
#define N_EDGES 400000
#define DIM     128
#define NREL    8
#define NBASES  4
#define KCAT    1152            // 8*128 relation slices + 128 self-loop
#define TN      16              // nodes per mega-block
#define TROW    4624            // Tf row stride bytes: (1152+4) f32, 1156%32=4 -> 2-way banks

typedef __hip_bfloat16 bf16;

typedef __bf16 bf16x8 __attribute__((ext_vector_type(8)));
typedef float  f32x4  __attribute__((ext_vector_type(4)));

union frag_u { bf16x8 v; bf16 e[8]; };
union pack4_u { unsigned long long ll; bf16 b[4]; };

// ---- workspace layout (bytes) ----
// hb16  bf16 [N][D]      : 12,800,000
// recs  uint2 [E]        :  3,200,000  (key=(src<<7)|((dst&15)<<3)|et, bits(norm))
// hist2 int [N*8]        :  1,600,000  (per-(node,et) counts; memset 0)
// cur2  int [N*8]        :  1,600,000  (absolute cursors, written by k_sub)
// deg   int [N] pad      :    200,064
// base  int [N+1] pad    :    200,064
// WcatT bf16 [D][KCAT]   :    294,912
// fwTb  bf16 [D][D]      :     32,768
#define HB16_OFF  0LL
#define RECS_OFF  12800000LL
#define HIST_OFF  16000000LL
#define CUR2_OFF  17600000LL
#define DEG_OFF   19200000LL
#define BASE_OFF  19400064LL
#define WCAT_OFF  19600128LL
#define FWT_OFF   19895040LL
#define WS_NEEDED 19927808LL

__device__ __forceinline__ int swzb(int row) { return (row & 15) << 4; }  // 256B rows
__device__ __forceinline__ int swzy(int row) { return (row & 31) << 4; }  // 512B rows

// ---------------------------------------------------------------------------
// K_prep: hb16 = bf16(h); hist2[(dst,et)]++; WcatT; fwTb.
__global__ __launch_bounds__(256)
void k_prep(const float* __restrict__ h, const float* __restrict__ V,
            const float* __restrict__ wc,
            const float* __restrict__ loop_w, const float* __restrict__ ffn_w,
            const int* __restrict__ dst, const int* __restrict__ et,
            bf16* __restrict__ hb, bf16* __restrict__ WcatT,
            bf16* __restrict__ fwTb, int* __restrict__ hist2) {
    int p = blockIdx.x * 256 + threadIdx.x;
    if (p < N_NODES * DIM / 8) {
        const float* s = h + (long long)p * 8;
        f32x4 lo = *(const f32x4*)s, hi = *(const f32x4*)(s + 4);
        frag_u o;
#pragma unroll
        for (int j = 0; j < 4; ++j) {
            o.e[j]     = __float2bfloat16(lo[j]);
            o.e[4 + j] = __float2bfloat16(hi[j]);
        }
        *(bf16x8*)(hb + (long long)p * 8) = o.v;
    }
    if (p < N_EDGES) atomicAdd(&hist2[dst[p] * 8 + et[p]], 1);
    if (p < DIM * KCAT) {
        int o = p / KCAT, k = p % KCAT;
        float val;
        if (k < 1024) {
            int r = k >> 7, i = k & 127;
            val = 0.f;
#pragma unroll
            for (int b = 0; b < NBASES; ++b)
                val += wc[r * NBASES + b] * V[(b << 14) + i * DIM + o];
        } else {
            val = loop_w[(k - 1024) * DIM + o];
        }
        WcatT[p] = __float2bfloat16(val);
    }
    if (p < DIM * DIM) fwTb[p] = __float2bfloat16(ffn_w[p]);
}

// ---------------------------------------------------------------------------
// K_deg: deg[d] = sum_et hist2[d][et]
__global__ __launch_bounds__(256)
void k_deg(const int* __restrict__ hist2, int* __restrict__ deg) {
    int d = blockIdx.x * 256 + threadIdx.x;
    if (d < N_NODES) {
        int4 a = *(const int4*)(hist2 + d * 8);
        int4 b = *(const int4*)(hist2 + d * 8 + 4);
        deg[d] = a.x + a.y + a.z + a.w + b.x + b.y + b.z + b.w;
    }
}

// ---------------------------------------------------------------------------
// K_scan: exclusive prefix sum of deg -> base. 1 block, 1024 thr.
#define SCAN_V 13
__global__ __launch_bounds__(1024)
void k_scan(const int* __restrict__ deg, int* __restrict__ base) {
    __shared__ int wsum[16];
    const int t = threadIdx.x, lane = t & 63, wv = t >> 6;
    const int i0 = t * (SCAN_V * 4);
    int4 v[SCAN_V];
#pragma unroll
    for (int i = 0; i < SCAN_V; ++i) {
        int idx = i0 + i * 4;
        if (idx + 3 < N_NODES) v[i] = *(const int4*)(deg + idx);
        else {
            v[i].x = (idx + 0 < N_NODES) ? deg[idx + 0] : 0;
            v[i].y = (idx + 1 < N_NODES) ? deg[idx + 1] : 0;
            v[i].z = (idx + 2 < N_NODES) ? deg[idx + 2] : 0;
            v[i].w = (idx + 3 < N_NODES) ? deg[idx + 3] : 0;
        }
    }
    int s = 0;
#pragma unroll
    for (int i = 0; i < SCAN_V; ++i) s += v[i].x + v[i].y + v[i].z + v[i].w;
    int inc = s;
#pragma unroll
    for (int m = 1; m < 64; m <<= 1) {
        int u = __shfl_up(inc, m);
        if (lane >= m) inc += u;
    }
    if (lane == 63) wsum[wv] = inc;
    __syncthreads();
    if (t < 16) {
        int w = wsum[t];
        int winc = w;
#pragma unroll
        for (int m = 1; m < 16; m <<= 1) {
            int u = __shfl_up(winc, m);
            if (t >= m) winc += u;
        }
        wsum[t] = winc - w;
    }
    __syncthreads();
    int run = wsum[wv] + (inc - s);
#pragma unroll
    for (int i = 0; i < SCAN_V; ++i) {
        int idx = i0 + i * 4;
        if (idx + 3 < N_NODES) {
            int4 o;
            o.x = run; o.y = o.x + v[i].x; o.z = o.y + v[i].y; o.w = o.z + v[i].z;
            run = o.w + v[i].w;
            *(int4*)(base + idx) = o;
        } else {
            if (idx + 0 < N_NODES) { base[idx+0] = run; run += v[i].x; }
            if (idx + 1 < N_NODES) { base[idx+1] = run; run += v[i].y; }
            if (idx + 2 < N_NODES) { base[idx+2] = run; run += v[i].z; }
            if (idx + 3 < N_NODES) { base[idx+3] = run; run += v[i].w; }
        }
    }
    if (t == 1023) base[N_NODES] = run;
}

// ---------------------------------------------------------------------------
// K_sub: cur2[d][et] = base[d] + exclusive-prefix_et(hist2[d][.])
__global__ __launch_bounds__(256)
void k_sub(const int* __restrict__ hist2, const int* __restrict__ base,
           int* __restrict__ cur2) {
    int d = blockIdx.x * 256 + threadIdx.x;
    if (d < N_NODES) {
        int4 a = *(const int4*)(hist2 + d * 8);
        int4 b = *(const int4*)(hist2 + d * 8 + 4);
        int run = base[d];
        int4 oa, ob;
        oa.x = run; run += a.x;
        oa.y = run; run += a.y;
        oa.z = run; run += a.z;
        oa.w = run; run += a.w;
        ob.x = run; run += b.x;
        ob.y = run; run += b.y;
        ob.z = run; run += b.z;
        ob.w = run;
        *(int4*)(cur2 + d * 8)     = oa;
        *(int4*)(cur2 + d * 8 + 4) = ob;
    }
}

// ---------------------------------------------------------------------------
// K_scatter: bucket edges by (dst, et). recs = {(src<<7)|((dst&15)<<3)|et, norm}
__global__ __launch_bounds__(256)
void k_scatter(const int* __restrict__ src, const int* __restrict__ dst,
               const int* __restrict__ et, const float* __restrict__ norm,
               int* __restrict__ cur2, uint2* __restrict__ recs) {
    int e = blockIdx.x * 256 + threadIdx.x;
    if (e >= N_EDGES) return;
    int d = dst[e], r = et[e];
    int pos = atomicAdd(&cur2[d * 8 + r], 1);
    uint2 rc;
    rc.x = ((unsigned)src[e] << 7) | (((unsigned)d & 15u) << 3) | (unsigned)r;
    rc.y = __float_as_uint(norm[e]);
    recs[pos] = rc;
}

// ---------------------------------------------------------------------------
// K_mega: 16 nodes/block, 256 thr (4 waves), LDS ~76 KB -> 2 blocks/CU.
//  P0 zero Tf agg region; P1a self-loop slice (f32); P1b edge-parallel gather:
//     16-lane group per edge, coalesced 256B hb16 row load (L2-resident),
//     8x LDS atomicAdd f32 into Tf[dstlocal][et*128+..]. No reg accumulators.
//  P2 MFMA: hn = relu(Tcat @ Wcat + bias)  [K=1152] -> hnb (bf16 swz)
//  P3 MFMA: y  = hn @ ffn_w^T + ffn_b + h  [K=128]  -> aggy (aliases Tf)
//  P4 LayerNorm -> out
__global__ __launch_bounds__(256)
void k_mega(const bf16* __restrict__ hb16, const uint2* __restrict__ recs,
            const int* __restrict__ base, const bf16* __restrict__ WcatT,
            const float* __restrict__ bias,
            const bf16* __restrict__ fwTb, const float* __restrict__ ffn_b,
            const float* __restrict__ ln_g, const float* __restrict__ ln_b,
            float* __restrict__ out) {
    __shared__ __align__(16) char Tf[TN * TROW];    // 73,984 B f32 (padded rows)
    __shared__ __align__(16) char hnb[TN * 256];    // 4 KB bf16 swz
    char* aggy = Tf;                                // alias for P3/P4
    const int t = threadIdx.x, wv = t >> 6, l = t & 63;
    const int n0 = blockIdx.x * TN;

    // ---- P0: zero agg region [0, 4096) of each row ----
    {
        const f32x4 z4{0.f, 0.f, 0.f, 0.f};
#pragma unroll
        for (int u = t; u < TN * 256; u += 256) {
            int row = u >> 8, u16 = u & 255;
            *(f32x4*)(Tf + row * TROW + u16 * 16) = z4;
        }
    }
    __syncthreads();

    const int g = t >> 4, c = t & 15;

    // ---- P1a: self-loop slice (k=1024..1151), disjoint from atomics ----
    {
        const int row = g;   // 16 groups == 16 rows
        frag_u sf;
        sf.v = *(const bf16x8*)(hb16 + (long long)(n0 + row) * DIM + c * 8);
        f32x4 lo, hi;
#pragma unroll
        for (int j = 0; j < 4; ++j) {
            lo[j] = __bfloat162float(sf.e[j]);
            hi[j] = __bfloat162float(sf.e[4 + j]);
        }
        char* pb = Tf + row * TROW + (1024 + c * 8) * 4;
        *(f32x4*)pb = lo;
        *(f32x4*)(pb + 16) = hi;
    }

    // ---- P1b: gather. Block edge range, 16-lane group per edge, stride 16,
    //           manual 2x unroll for 2 rows in flight per group. ----
    {
        const int b0 = base[n0], b1 = base[n0 + TN];
        for (int e = b0 + g; e < b1; e += 32) {
            const int e2 = e + 16;
            const bool v2 = e2 < b1;
            const uint2 m1 = recs[e];
            const uint2 m2 = recs[v2 ? e2 : e];
            frag_u f1, f2;
            f1.v = *(const bf16x8*)(hb16 + (long long)(m1.x >> 7) * DIM + c * 8);
            f2.v = *(const bf16x8*)(hb16 + (long long)(m2.x >> 7) * DIM + c * 8);
            {
                const float w = __uint_as_float(m1.y);
                float* d0 = (float*)(Tf + ((m1.x >> 3) & 15u) * TROW) +
                            ((m1.x & 7u) * 128 + c * 8);
#pragma unroll
                for (int q = 0; q < 8; ++q)
                    atomicAdd(d0 + q, w * __bfloat162float(f1.e[q]));
            }
            if (v2) {
                const float w = __uint_as_float(m2.y);
                float* d0 = (float*)(Tf + ((m2.x >> 3) & 15u) * TROW) +
                            ((m2.x & 7u) * 128 + c * 8);
#pragma unroll
                for (int q = 0; q < 8; ++q)
                    atomicAdd(d0 + q, w * __bfloat162float(f2.e[q]));
            }
        }
    }
    __syncthreads();

    // ---- P2: hn = relu(Tcat @ Wcat + bias), K=1152. Wave wv: cols wv*32..+31,
    //          rows 0..15 (arow = lrow). A read f32 from Tf, cvt to bf16. ----
    const int lrow = l & 15, kgrp = l >> 4;
    const int cw = wv * 32;
    {
        f32x4 acc1[2];
#pragma unroll
        for (int nt = 0; nt < 2; ++nt) acc1[nt] = f32x4{0.f, 0.f, 0.f, 0.f};
        const char* arow_p = Tf + lrow * TROW;
#pragma unroll 4
        for (int ks = 0; ks < KCAT / 32; ++ks) {
            const int k = ks * 32 + kgrp * 8;
            f32x4 a0 = *(const f32x4*)(arow_p + k * 4);
            f32x4 a1 = *(const f32x4*)(arow_p + k * 4 + 16);
            frag_u a;
#pragma unroll
            for (int j = 0; j < 4; ++j) {
                a.e[j]     = __float2bfloat16(a0[j]);
                a.e[4 + j] = __float2bfloat16(a1[j]);
            }
#pragma unroll
            for (int nt = 0; nt < 2; ++nt) {
                frag_u b;
                b.v = *(const bf16x8*)(WcatT +
                        (long long)(cw + nt * 16 + lrow) * KCAT + k);
                acc1[nt] = __builtin_amdgcn_mfma_f32_16x16x32_bf16(
                    b.v, a.v, acc1[nt], 0, 0, 0);
            }
        }
        const int xb = swzb(lrow);
#pragma unroll
        for (int nt = 0; nt < 2; ++nt) {
            int col = cw + nt * 16 + kgrp * 4;
            f32x4 bi = *(const f32x4*)(bias + col);
            pack4_u p;
#pragma unroll
            for (int j = 0; j < 4; ++j)
                p.b[j] = __float2bfloat16(fmaxf(acc1[nt][j] + bi[j], 0.f));
            *(unsigned long long*)(hnb + ((lrow * 256 + col * 2) ^ xb)) = p.ll;
        }
    }
    __syncthreads();

    // ---- P3: y = hn @ ffn_w^T + ffn_b + h, K=128 -> aggy (aliases Tf) ----
    {
        f32x4 acc2[2];
#pragma unroll
        for (int nt = 0; nt < 2; ++nt) acc2[nt] = f32x4{0.f, 0.f, 0.f, 0.f};
        const int xb = swzb(lrow);
#pragma unroll
        for (int ks = 0; ks < 4; ++ks) {
            const int k = ks * 32 + kgrp * 8;
            frag_u a;
            a.v = *(const bf16x8*)(hnb + ((lrow * 256 + k * 2) ^ xb));
#pragma unroll
            for (int nt = 0; nt < 2; ++nt) {
                frag_u b;
                b.v = *(const bf16x8*)(fwTb + (cw + nt * 16 + lrow) * DIM + k);
                acc2[nt] = __builtin_amdgcn_mfma_f32_16x16x32_bf16(
                    b.v, a.v, acc2[nt], 0, 0, 0);
            }
        }
        const int xy = swzy(lrow);
#pragma unroll
        for (int nt = 0; nt < 2; ++nt) {
            int col = cw + nt * 16 + kgrp * 4;
            f32x4 fb = *(const f32x4*)(ffn_b + col);
            pack4_u hp;
            hp.ll = *(const unsigned long long*)(hb16 +
                      (long long)(n0 + lrow) * DIM + col);
            f32x4 y;
#pragma unroll
            for (int j = 0; j < 4; ++j)
                y[j] = acc2[nt][j] + fb[j] + __bfloat162float(hp.b[j]);
            *(f32x4*)(aggy + lrow * 512 + ((col * 4) ^ xy)) = y;
        }
    }
    __syncthreads();

    // ---- P4: LayerNorm. 4 waves x 4 rows. Addr swizzled; col = PRE-swz 2l. ----
#pragma unroll 1
    for (int jr = 0; jr < 4; ++jr) {
        const int row = wv * 4 + jr;
        const int nn = n0 + row;
        const int x = swzy(row);
        float2 yv = *(const float2*)(aggy + row * 512 + ((l * 8) ^ x));
        const int col = l * 2;
        float s = yv.x + yv.y, s2 = yv.x * yv.x + yv.y * yv.y;
#pragma unroll
        for (int m = 1; m < 64; m <<= 1) {
            s  += __shfl_xor(s, m);
            s2 += __shfl_xor(s2, m);
        }
        float mu  = s * (1.f / DIM);
        float var = s2 * (1.f / DIM) - mu * mu;
        float inv = rsqrtf(var + 1e-8f);
        float2 gv = *(const float2*)(ln_g + col);
        float2 bv = *(const float2*)(ln_b + col);
        float2 o2{(yv.x - mu) * inv * gv.x + bv.x,
                  (yv.y - mu) * inv * gv.y + bv.y};
        *(float2*)(out + (long long)nn * DIM + col) = o2;
    }
}

// ---------------------------------------------------------------------------
extern "C" void kernel_launch(void* const* d_in, const int* in_sizes, int n_in,
                              void* d_out, int out_size, void* d_ws, size_t ws_size,
                              hipStream_t stream) {
    const float* h      = (const float*)d_in[0];
    const float* V      = (const float*)d_in[1];
    const float* w_comp = (const float*)d_in[2];
    const float* loop_w = (const float*)d_in[3];
    const float* bias   = (const float*)d_in[4];
    const float* ffn_w  = (const float*)d_in[5];
    const float* ffn_b  = (const float*)d_in[6];
    const float* ln_g   = (const float*)d_in[7];
    const float* ln_b   = (const float*)d_in[8];
    const float* norm   = (const float*)d_in[9];
    const int*   src    = (const int*)d_in[10];
    const int*   dst    = (const int*)d_in[11];
    const int*   etype  = (const int*)d_in[12];
    float* out = (float*)d_out;

    if (ws_size < (size_t)WS_NEEDED) return;

    char* ws = (char*)d_ws;
    bf16*  hb16  = (bf16*)(ws + HB16_OFF);
    uint2* recs  = (uint2*)(ws + RECS_OFF);
    int*   hist2 = (int*)(ws + HIST_OFF);
    int*   cur2  = (int*)(ws + CUR2_OFF);
    int*   deg   = (int*)(ws + DEG_OFF);
    int*   base  = (int*)(ws + BASE_OFF);
    bf16*  WcatT = (bf16*)(ws + WCAT_OFF);
    bf16*  fwTb  = (bf16*)(ws + FWT_OFF);

    hipMemsetAsync(hist2, 0, N_NODES * NREL * sizeof(int), stream);

    k_prep<<<dim3(3125), dim3(256), 0, stream>>>(
        h, V, w_comp, loop_w, ffn_w, dst, etype, hb16, WcatT, fwTb, hist2);

    k_deg<<<dim3((N_NODES + 255) / 256), dim3(256), 0, stream>>>(hist2, deg);
    k_scan<<<dim3(1), dim3(1024), 0, stream>>>(deg, base);
    k_sub<<<dim3((N_NODES + 255) / 256), dim3(256), 0, stream>>>(hist2, base, cur2);
    k_scatter<<<dim3((N_EDGES + 255) / 256), dim3(256), 0, stream>>>(
        src, dst, etype, norm, cur2, recs);

    k_mega<<<dim3(N_NODES / TN), dim3(256), 0, stream>>>(
        hb16, recs, base, WcatT, bias, fwTb, ffn_b, ln_g, ln_b, out);
}

// Round 10
// 217.214 us; speedup vs baseline: 2.0700x; 2.0700x over previous
//
#include <hip/hip_runtime.h>
#include <hip/hip_bf16.h>

#define N_NODES 50000
#define N_EDGES 400000
#define DIM     128
#define NREL    8
#define NBASES  4
#define KCAT    1152            // 8*128 relation slices + 128 self-loop
#define TN      16              // nodes per mega-block
#define TROW    2320            // Tcat bf16 row stride bytes (1160 bf16; 2-way banks)

typedef __hip_bfloat16 bf16;

typedef __bf16 bf16x8 __attribute__((ext_vector_type(8)));
typedef float  f32x4  __attribute__((ext_vector_type(4)));

union frag_u { bf16x8 v; bf16 e[8]; };
union pack4_u { unsigned long long ll; bf16 b[4]; };

// ---- workspace layout (bytes) ----
// hb16  bf16 [N][D]      : 12,800,000
// recs  uint2 [E]        :  3,200,000  (key=(src<<3)|et, bits(norm); (dst,et)-sorted)
// hist2 int [N*8]        :  1,600,000
// cur2  int [N*8]        :  1,600,000
// deg   int [N] pad      :    200,064
// base  int [N+1] pad    :    200,064
// WcatT bf16 [D][KCAT]   :    294,912
// fwTb  bf16 [D][D]      :     32,768
#define HB16_OFF  0LL
#define RECS_OFF  12800000LL
#define HIST_OFF  16000000LL
#define CUR2_OFF  17600000LL
#define DEG_OFF   19200000LL
#define BASE_OFF  19400064LL
#define WCAT_OFF  19600128LL
#define FWT_OFF   19895040LL
#define WS_NEEDED 19927808LL

__device__ __forceinline__ int swzb(int row) { return (row & 15) << 4; }  // 256B rows
__device__ __forceinline__ int swzy(int row) { return (row & 31) << 4; }  // 512B rows

// ---------------------------------------------------------------------------
// K_prep: hb16 = bf16(h); hist2[(dst,et)]++; WcatT; fwTb.
__global__ __launch_bounds__(256)
void k_prep(const float* __restrict__ h, const float* __restrict__ V,
            const float* __restrict__ wc,
            const float* __restrict__ loop_w, const float* __restrict__ ffn_w,
            const int* __restrict__ dst, const int* __restrict__ et,
            bf16* __restrict__ hb, bf16* __restrict__ WcatT,
            bf16* __restrict__ fwTb, int* __restrict__ hist2) {
    int p = blockIdx.x * 256 + threadIdx.x;
    if (p < N_NODES * DIM / 8) {
        const float* s = h + (long long)p * 8;
        f32x4 lo = *(const f32x4*)s, hi = *(const f32x4*)(s + 4);
        frag_u o;
#pragma unroll
        for (int j = 0; j < 4; ++j) {
            o.e[j]     = __float2bfloat16(lo[j]);
            o.e[4 + j] = __float2bfloat16(hi[j]);
        }
        *(bf16x8*)(hb + (long long)p * 8) = o.v;
    }
    if (p < N_EDGES) atomicAdd(&hist2[dst[p] * 8 + et[p]], 1);
    if (p < DIM * KCAT) {
        int o = p / KCAT, k = p % KCAT;
        float val;
        if (k < 1024) {
            int r = k >> 7, i = k & 127;
            val = 0.f;
#pragma unroll
            for (int b = 0; b < NBASES; ++b)
                val += wc[r * NBASES + b] * V[(b << 14) + i * DIM + o];
        } else {
            val = loop_w[(k - 1024) * DIM + o];
        }
        WcatT[p] = __float2bfloat16(val);
    }
    if (p < DIM * DIM) fwTb[p] = __float2bfloat16(ffn_w[p]);
}

// ---------------------------------------------------------------------------
// K_deg: deg[d] = sum_et hist2[d][et]
__global__ __launch_bounds__(256)
void k_deg(const int* __restrict__ hist2, int* __restrict__ deg) {
    int d = blockIdx.x * 256 + threadIdx.x;
    if (d < N_NODES) {
        int4 a = *(const int4*)(hist2 + d * 8);
        int4 b = *(const int4*)(hist2 + d * 8 + 4);
        deg[d] = a.x + a.y + a.z + a.w + b.x + b.y + b.z + b.w;
    }
}

// ---------------------------------------------------------------------------
// K_scan: exclusive prefix sum of deg -> base. 1 block, 1024 thr.
#define SCAN_V 13
__global__ __launch_bounds__(1024)
void k_scan(const int* __restrict__ deg, int* __restrict__ base) {
    __shared__ int wsum[16];
    const int t = threadIdx.x, lane = t & 63, wv = t >> 6;
    const int i0 = t * (SCAN_V * 4);
    int4 v[SCAN_V];
#pragma unroll
    for (int i = 0; i < SCAN_V; ++i) {
        int idx = i0 + i * 4;
        if (idx + 3 < N_NODES) v[i] = *(const int4*)(deg + idx);
        else {
            v[i].x = (idx + 0 < N_NODES) ? deg[idx + 0] : 0;
            v[i].y = (idx + 1 < N_NODES) ? deg[idx + 1] : 0;
            v[i].z = (idx + 2 < N_NODES) ? deg[idx + 2] : 0;
            v[i].w = (idx + 3 < N_NODES) ? deg[idx + 3] : 0;
        }
    }
    int s = 0;
#pragma unroll
    for (int i = 0; i < SCAN_V; ++i) s += v[i].x + v[i].y + v[i].z + v[i].w;
    int inc = s;
#pragma unroll
    for (int m = 1; m < 64; m <<= 1) {
        int u = __shfl_up(inc, m);
        if (lane >= m) inc += u;
    }
    if (lane == 63) wsum[wv] = inc;
    __syncthreads();
    if (t < 16) {
        int w = wsum[t];
        int winc = w;
#pragma unroll
        for (int m = 1; m < 16; m <<= 1) {
            int u = __shfl_up(winc, m);
            if (t >= m) winc += u;
        }
        wsum[t] = winc - w;
    }
    __syncthreads();
    int run = wsum[wv] + (inc - s);
#pragma unroll
    for (int i = 0; i < SCAN_V; ++i) {
        int idx = i0 + i * 4;
        if (idx + 3 < N_NODES) {
            int4 o;
            o.x = run; o.y = o.x + v[i].x; o.z = o.y + v[i].y; o.w = o.z + v[i].z;
            run = o.w + v[i].w;
            *(int4*)(base + idx) = o;
        } else {
            if (idx + 0 < N_NODES) { base[idx+0] = run; run += v[i].x; }
            if (idx + 1 < N_NODES) { base[idx+1] = run; run += v[i].y; }
            if (idx + 2 < N_NODES) { base[idx+2] = run; run += v[i].z; }
            if (idx + 3 < N_NODES) { base[idx+3] = run; run += v[i].w; }
        }
    }
    if (t == 1023) base[N_NODES] = run;
}

// ---------------------------------------------------------------------------
// K_sub: cur2[d][et] = base[d] + exclusive-prefix_et(hist2[d][.])
__global__ __launch_bounds__(256)
void k_sub(const int* __restrict__ hist2, const int* __restrict__ base,
           int* __restrict__ cur2) {
    int d = blockIdx.x * 256 + threadIdx.x;
    if (d < N_NODES) {
        int4 a = *(const int4*)(hist2 + d * 8);
        int4 b = *(const int4*)(hist2 + d * 8 + 4);
        int run = base[d];
        int4 oa, ob;
        oa.x = run; run += a.x;
        oa.y = run; run += a.y;
        oa.z = run; run += a.z;
        oa.w = run; run += a.w;
        ob.x = run; run += b.x;
        ob.y = run; run += b.y;
        ob.z = run; run += b.z;
        ob.w = run;
        *(int4*)(cur2 + d * 8)     = oa;
        *(int4*)(cur2 + d * 8 + 4) = ob;
    }
}

// ---------------------------------------------------------------------------
// K_scatter: bucket edges by (dst, et). recs = {(src<<3)|et, bits(norm)}.
__global__ __launch_bounds__(256)
void k_scatter(const int* __restrict__ src, const int* __restrict__ dst,
               const int* __restrict__ et, const float* __restrict__ norm,
               int* __restrict__ cur2, uint2* __restrict__ recs) {
    int e = blockIdx.x * 256 + threadIdx.x;
    if (e >= N_EDGES) return;
    int d = dst[e], r = et[e];
    int pos = atomicAdd(&cur2[d * 8 + r], 1);
    uint2 rc;
    rc.x = ((unsigned)src[e] << 3) | (unsigned)r;
    rc.y = __float_as_uint(norm[e]);
    recs[pos] = rc;
}

// ---------------------------------------------------------------------------
// K_mega: 16 nodes/block, 256 thr (4 waves), LDS ~41 KB -> 3 blocks/CU.
//  P0 zero Tcat relation region (bf16); P1a self-loop slice (bf16 copy);
//  P1b gather: 16-lane group per node; edges (dst,et)-SORTED so each (node,et)
//      run is contiguous -> single acc[8] f32 in REGISTERS, flushed once per
//      et-run as a plain bf16x8 store (single owner, no atomics, no spill).
//      4-edge unroll = 4 independent row loads in flight per group.
//  P2 MFMA: hn = relu(Tcat @ Wcat + bias)  [K=1152] -> hnb (bf16 swz)
//  P3 MFMA: y  = hn @ ffn_w^T + ffn_b + h  [K=128]  -> aggy (aliases Tcat)
//  P4 LayerNorm -> out
__global__ __launch_bounds__(256)
void k_mega(const bf16* __restrict__ hb16, const uint2* __restrict__ recs,
            const int* __restrict__ base, const bf16* __restrict__ WcatT,
            const float* __restrict__ bias,
            const bf16* __restrict__ fwTb, const float* __restrict__ ffn_b,
            const float* __restrict__ ln_g, const float* __restrict__ ln_b,
            float* __restrict__ out) {
    __shared__ __align__(16) char Tf[TN * TROW];    // 37,120 B bf16 Tcat
    __shared__ __align__(16) char hnb[TN * 256];    // 4 KB bf16 swz
    char* aggy = Tf;                                // 8 KB alias for P3/P4
    const int t = threadIdx.x, wv = t >> 6, l = t & 63;
    const int n0 = blockIdx.x * TN;

    // ---- P0: zero relation region [0, 2048)B of each row ----
    {
        const f32x4 z4{0.f, 0.f, 0.f, 0.f};
#pragma unroll
        for (int u = t; u < TN * 128; u += 256) {
            int row = u >> 7, off = (u & 127) * 16;
            *(f32x4*)(Tf + row * TROW + off) = z4;
        }
    }
    __syncthreads();

    const int grp = t >> 4, c = t & 15;
    const int gbase = l & 48;            // group's base lane within wave
    const int n = n0 + grp;
    const int rowb = grp * TROW;

    // ---- P1a: self-loop slice (bytes 2048..2304): direct bf16 copy ----
    *(bf16x8*)(Tf + rowb + 2048 + c * 16) =
        *(const bf16x8*)(hb16 + (long long)n * DIM + c * 8);

    // ---- P1b: gather (sorted runs -> reg acc + flush per et) ----
    {
        const int b0 = base[n], b1 = base[n + 1];
        float acc[8];
#pragma unroll
        for (int q = 0; q < 8; ++q) acc[q] = 0.f;
        int cur_et = -1;

        auto flush = [&]() {
            frag_u o;
#pragma unroll
            for (int q = 0; q < 8; ++q) o.e[q] = __float2bfloat16(acc[q]);
            *(bf16x8*)(Tf + rowb + cur_et * 256 + c * 16) = o.v;
#pragma unroll
            for (int q = 0; q < 8; ++q) acc[q] = 0.f;
        };

        for (int eb = b0; eb < b1; eb += 4) {
            const int rem = b1 - eb;
            uint2 md = (c < 4 && c < rem) ? recs[eb + c] : uint2{0u, 0u};
            const unsigned sk0 = (unsigned)__shfl((int)md.x, gbase + 0);
            const unsigned sk1 = (unsigned)__shfl((int)md.x, gbase + 1);
            const unsigned sk2 = (unsigned)__shfl((int)md.x, gbase + 2);
            const unsigned sk3 = (unsigned)__shfl((int)md.x, gbase + 3);
            const float wk0 = __uint_as_float(__shfl((int)md.y, gbase + 0));
            const float wk1 = __uint_as_float(__shfl((int)md.y, gbase + 1));
            const float wk2 = __uint_as_float(__shfl((int)md.y, gbase + 2));
            const float wk3 = __uint_as_float(__shfl((int)md.y, gbase + 3));
            frag_u f0, f1, f2, f3;   // 4 independent loads in flight
            f0.v = *(const bf16x8*)(hb16 + (long long)(sk0 >> 3) * DIM + c * 8);
            f1.v = *(const bf16x8*)(hb16 + (long long)(sk1 >> 3) * DIM + c * 8);
            f2.v = *(const bf16x8*)(hb16 + (long long)(sk2 >> 3) * DIM + c * 8);
            f3.v = *(const bf16x8*)(hb16 + (long long)(sk3 >> 3) * DIM + c * 8);

#define STEP(K, SK, WK, FK)                                              \
            if (K < rem) {                                               \
                const int et_ = (int)(SK & 7u);                          \
                if (et_ != cur_et) {                                     \
                    if (cur_et >= 0) flush();                            \
                    cur_et = et_;                                        \
                }                                                        \
                _Pragma("unroll")                                        \
                for (int q = 0; q < 8; ++q)                              \
                    acc[q] = fmaf(WK, __bfloat162float(FK.e[q]), acc[q]);\
            }
            STEP(0, sk0, wk0, f0)
            STEP(1, sk1, wk1, f1)
            STEP(2, sk2, wk2, f2)
            STEP(3, sk3, wk3, f3)
#undef STEP
        }
        if (cur_et >= 0) flush();
    }
    __syncthreads();

    // ---- P2: hn = relu(Tcat @ Wcat + bias), K=1152.
    //      Wave wv: cols wv*32..+31, rows 0..15 (arow = lrow). ----
    const int lrow = l & 15, kgrp = l >> 4;
    const int cw = wv * 32;
    {
        f32x4 acc1[2];
#pragma unroll
        for (int nt = 0; nt < 2; ++nt) acc1[nt] = f32x4{0.f, 0.f, 0.f, 0.f};
        const char* arow_p = Tf + lrow * TROW;
#pragma unroll 4
        for (int ks = 0; ks < KCAT / 32; ++ks) {
            frag_u a;
            a.v = *(const bf16x8*)(arow_p + ks * 64 + kgrp * 16);
#pragma unroll
            for (int nt = 0; nt < 2; ++nt) {
                frag_u b;
                b.v = *(const bf16x8*)(WcatT +
                        (long long)(cw + nt * 16 + lrow) * KCAT +
                        ks * 32 + kgrp * 8);
                acc1[nt] = __builtin_amdgcn_mfma_f32_16x16x32_bf16(
                    b.v, a.v, acc1[nt], 0, 0, 0);
            }
        }
        const int xb = swzb(lrow);
#pragma unroll
        for (int nt = 0; nt < 2; ++nt) {
            int col = cw + nt * 16 + kgrp * 4;
            f32x4 bi = *(const f32x4*)(bias + col);
            pack4_u p;
#pragma unroll
            for (int j = 0; j < 4; ++j)
                p.b[j] = __float2bfloat16(fmaxf(acc1[nt][j] + bi[j], 0.f));
            *(unsigned long long*)(hnb + ((lrow * 256 + col * 2) ^ xb)) = p.ll;
        }
    }
    __syncthreads();

    // ---- P3: y = hn @ ffn_w^T + ffn_b + h, K=128 -> aggy (aliases Tf) ----
    {
        f32x4 acc2[2];
#pragma unroll
        for (int nt = 0; nt < 2; ++nt) acc2[nt] = f32x4{0.f, 0.f, 0.f, 0.f};
        const int xb = swzb(lrow);
#pragma unroll
        for (int ks = 0; ks < 4; ++ks) {
            const int k = ks * 32 + kgrp * 8;
            frag_u a;
            a.v = *(const bf16x8*)(hnb + ((lrow * 256 + k * 2) ^ xb));
#pragma unroll
            for (int nt = 0; nt < 2; ++nt) {
                frag_u b;
                b.v = *(const bf16x8*)(fwTb + (cw + nt * 16 + lrow) * DIM + k);
                acc2[nt] = __builtin_amdgcn_mfma_f32_16x16x32_bf16(
                    b.v, a.v, acc2[nt], 0, 0, 0);
            }
        }
        const int xy = swzy(lrow);
#pragma unroll
        for (int nt = 0; nt < 2; ++nt) {
            int col = cw + nt * 16 + kgrp * 4;
            f32x4 fb = *(const f32x4*)(ffn_b + col);
            pack4_u hp;
            hp.ll = *(const unsigned long long*)(hb16 +
                      (long long)(n0 + lrow) * DIM + col);
            f32x4 y;
#pragma unroll
            for (int j = 0; j < 4; ++j)
                y[j] = acc2[nt][j] + fb[j] + __bfloat162float(hp.b[j]);
            *(f32x4*)(aggy + lrow * 512 + ((col * 4) ^ xy)) = y;
        }
    }
    __syncthreads();

    // ---- P4: LayerNorm. 4 waves x 4 rows. Addr swizzled; col = PRE-swz 2l. ----
#pragma unroll 1
    for (int jr = 0; jr < 4; ++jr) {
        const int row = wv * 4 + jr;
        const int nn = n0 + row;
        const int x = swzy(row);
        float2 yv = *(const float2*)(aggy + row * 512 + ((l * 8) ^ x));
        const int col = l * 2;
        float s = yv.x + yv.y, s2 = yv.x * yv.x + yv.y * yv.y;
#pragma unroll
        for (int m = 1; m < 64; m <<= 1) {
            s  += __shfl_xor(s, m);
            s2 += __shfl_xor(s2, m);
        }
        float mu  = s * (1.f / DIM);
        float var = s2 * (1.f / DIM) - mu * mu;
        float inv = rsqrtf(var + 1e-8f);
        float2 gv = *(const float2*)(ln_g + col);
        float2 bv = *(const float2*)(ln_b + col);
        float2 o2{(yv.x - mu) * inv * gv.x + bv.x,
                  (yv.y - mu) * inv * gv.y + bv.y};
        *(float2*)(out + (long long)nn * DIM + col) = o2;
    }
}

// ---------------------------------------------------------------------------
extern "C" void kernel_launch(void* const* d_in, const int* in_sizes, int n_in,
                              void* d_out, int out_size, void* d_ws, size_t ws_size,
                              hipStream_t stream) {
    const float* h      = (const float*)d_in[0];
    const float* V      = (const float*)d_in[1];
    const float* w_comp = (const float*)d_in[2];
    const float* loop_w = (const float*)d_in[3];
    const float* bias   = (const float*)d_in[4];
    const float* ffn_w  = (const float*)d_in[5];
    const float* ffn_b  = (const float*)d_in[6];
    const float* ln_g   = (const float*)d_in[7];
    const float* ln_b   = (const float*)d_in[8];
    const float* norm   = (const float*)d_in[9];
    const int*   src    = (const int*)d_in[10];
    const int*   dst    = (const int*)d_in[11];
    const int*   etype  = (const int*)d_in[12];
    float* out = (float*)d_out;

    if (ws_size < (size_t)WS_NEEDED) return;

    char* ws = (char*)d_ws;
    bf16*  hb16  = (bf16*)(ws + HB16_OFF);
    uint2* recs  = (uint2*)(ws + RECS_OFF);
    int*   hist2 = (int*)(ws + HIST_OFF);
    int*   cur2  = (int*)(ws + CUR2_OFF);
    int*   deg   = (int*)(ws + DEG_OFF);
    int*   base  = (int*)(ws + BASE_OFF);
    bf16*  WcatT = (bf16*)(ws + WCAT_OFF);
    bf16*  fwTb  = (bf16*)(ws + FWT_OFF);

    hipMemsetAsync(hist2, 0, N_NODES * NREL * sizeof(int), stream);

    k_prep<<<dim3(3125), dim3(256), 0, stream>>>(
        h, V, w_comp, loop_w, ffn_w, dst, etype, hb16, WcatT, fwTb, hist2);

    k_deg<<<dim3((N_NODES + 255) / 256), dim3(256), 0, stream>>>(hist2, deg);
    k_scan<<<dim3(1), dim3(1024), 0, stream>>>(deg, base);
    k_sub<<<dim3((N_NODES + 255) / 256), dim3(256), 0, stream>>>(hist2, base, cur2);
    k_scatter<<<dim3((N_EDGES + 255) / 256), dim3(256), 0, stream>>>(
        src, dst, etype, norm, cur2, recs);

    k_mega<<<dim3(N_NODES / TN), dim3(256), 0, stream>>>(
        hb16, recs, base, WcatT, bias, fwTb, ffn_b, ln_g, ln_b, out);
}

// Round 11
// 160.172 us; speedup vs baseline: 2.8071x; 1.3561x over previous
//
#include <hip/hip_runtime.h>
#include <hip/hip_bf16.h>

#define N_NODES 50000
#define N_EDGES 400000
#define DIM     128
#define NREL    8
#define NBASES  4
#define KCAT    1152            // 8*128 relation slices + 128 self-loop
#define NKS     36              // KCAT/32
#define TN      32              // nodes per mega-block
#define TROW    2320            // Tcat bf16 row stride bytes (145*16B, 145 odd -> spread)

typedef __hip_bfloat16 bf16;

typedef __bf16 bf16x8 __attribute__((ext_vector_type(8)));
typedef float  f32x4  __attribute__((ext_vector_type(4)));

union frag_u { bf16x8 v; bf16 e[8]; };
union pack4_u { unsigned long long ll; bf16 b[4]; };

// ---- workspace layout (bytes) ----
// hb16  bf16 [N][D]          : 12,800,000
// recs  uint2 [E]            :  3,200,000  ((dst,et)-sorted; key=(src<<3)|et)
// hist2 int [N*8]            :  1,600,000
// cur2  int [N*8]            :  1,600,000
// deg   int [N] pad          :    200,064
// base  int [N+1] pad        :    200,064
// WcatF bf16 [8][36][64][8]  :    294,912  (fragment-ordered stacked weights)
// fwF   bf16 [8][4][64][8]   :     32,768  (fragment-ordered ffn_w)
#define HB16_OFF  0LL
#define RECS_OFF  12800000LL
#define HIST_OFF  16000000LL
#define CUR2_OFF  17600000LL
#define DEG_OFF   19200000LL
#define BASE_OFF  19400064LL
#define WCAT_OFF  19600128LL
#define FWF_OFF   19895040LL
#define WS_NEEDED 19927808LL

__device__ __forceinline__ int swzb(int row) { return (row & 15) << 4; }  // 256B rows
__device__ __forceinline__ int swzy(int row) { return (row & 31) << 4; }  // 512B rows

// ---------------------------------------------------------------------------
// K_prep: hb16 = bf16(h); hist2[(dst,et)]++; WcatF/fwF in FRAGMENT ORDER:
//   WcatF element (ct,ks,l,j) = Wcat^T[ct*16+(l&15)][ks*32+(l>>4)*8+j]
//   so the B-fragment load in P2 is one coalesced 1KB segment per wave.
__global__ __launch_bounds__(256)
void k_prep(const float* __restrict__ h, const float* __restrict__ V,
            const float* __restrict__ wc,
            const float* __restrict__ loop_w, const float* __restrict__ ffn_w,
            const int* __restrict__ dst, const int* __restrict__ et,
            bf16* __restrict__ hb, bf16* __restrict__ WcatF,
            bf16* __restrict__ fwF, int* __restrict__ hist2) {
    int p = blockIdx.x * 256 + threadIdx.x;
    if (p < N_NODES * DIM / 8) {
        const float* s = h + (long long)p * 8;
        f32x4 lo = *(const f32x4*)s, hi = *(const f32x4*)(s + 4);
        frag_u o;
#pragma unroll
        for (int j = 0; j < 4; ++j) {
            o.e[j]     = __float2bfloat16(lo[j]);
            o.e[4 + j] = __float2bfloat16(hi[j]);
        }
        *(bf16x8*)(hb + (long long)p * 8) = o.v;
    }
    if (p < N_EDGES) atomicAdd(&hist2[dst[p] * 8 + et[p]], 1);
    if (p < NREL * DIM * KCAT / 8) { /* dummy guard to keep structure clear */ }
    if (p < 8 * NKS * 64 * 8) {            // 147456 WcatF elements
        int idx = p;
        int j = idx & 7; idx >>= 3;
        int l = idx & 63; idx >>= 6;
        int ks = idx % NKS, ct = idx / NKS;
        int col = ct * 16 + (l & 15);
        int k = ks * 32 + (l >> 4) * 8 + j;
        float val;
        if (k < 1024) {
            int r = k >> 7, i = k & 127;
            val = 0.f;
#pragma unroll
            for (int b = 0; b < NBASES; ++b)
                val += wc[r * NBASES + b] * V[(b << 14) + i * DIM + col];
        } else {
            val = loop_w[(k - 1024) * DIM + col];
        }
        WcatF[p] = __float2bfloat16(val);
    }
    if (p < 8 * 4 * 64 * 8) {              // 16384 fwF elements
        int idx = p;
        int j = idx & 7; idx >>= 3;
        int l = idx & 63; idx >>= 6;
        int ks = idx & 3, ct = idx >> 2;
        int col = ct * 16 + (l & 15);
        int k = ks * 32 + (l >> 4) * 8 + j;
        fwF[p] = __float2bfloat16(ffn_w[col * DIM + k]);   // ffn_w[o][i]
    }
}

// ---------------------------------------------------------------------------
// K_deg: deg[d] = sum_et hist2[d][et]
__global__ __launch_bounds__(256)
void k_deg(const int* __restrict__ hist2, int* __restrict__ deg) {
    int d = blockIdx.x * 256 + threadIdx.x;
    if (d < N_NODES) {
        int4 a = *(const int4*)(hist2 + d * 8);
        int4 b = *(const int4*)(hist2 + d * 8 + 4);
        deg[d] = a.x + a.y + a.z + a.w + b.x + b.y + b.z + b.w;
    }
}

// ---------------------------------------------------------------------------
// K_scan: exclusive prefix sum of deg -> base. 1 block, 1024 thr.
#define SCAN_V 13
__global__ __launch_bounds__(1024)
void k_scan(const int* __restrict__ deg, int* __restrict__ base) {
    __shared__ int wsum[16];
    const int t = threadIdx.x, lane = t & 63, wv = t >> 6;
    const int i0 = t * (SCAN_V * 4);
    int4 v[SCAN_V];
#pragma unroll
    for (int i = 0; i < SCAN_V; ++i) {
        int idx = i0 + i * 4;
        if (idx + 3 < N_NODES) v[i] = *(const int4*)(deg + idx);
        else {
            v[i].x = (idx + 0 < N_NODES) ? deg[idx + 0] : 0;
            v[i].y = (idx + 1 < N_NODES) ? deg[idx + 1] : 0;
            v[i].z = (idx + 2 < N_NODES) ? deg[idx + 2] : 0;
            v[i].w = (idx + 3 < N_NODES) ? deg[idx + 3] : 0;
        }
    }
    int s = 0;
#pragma unroll
    for (int i = 0; i < SCAN_V; ++i) s += v[i].x + v[i].y + v[i].z + v[i].w;
    int inc = s;
#pragma unroll
    for (int m = 1; m < 64; m <<= 1) {
        int u = __shfl_up(inc, m);
        if (lane >= m) inc += u;
    }
    if (lane == 63) wsum[wv] = inc;
    __syncthreads();
    if (t < 16) {
        int w = wsum[t];
        int winc = w;
#pragma unroll
        for (int m = 1; m < 16; m <<= 1) {
            int u = __shfl_up(winc, m);
            if (t >= m) winc += u;
        }
        wsum[t] = winc - w;
    }
    __syncthreads();
    int run = wsum[wv] + (inc - s);
#pragma unroll
    for (int i = 0; i < SCAN_V; ++i) {
        int idx = i0 + i * 4;
        if (idx + 3 < N_NODES) {
            int4 o;
            o.x = run; o.y = o.x + v[i].x; o.z = o.y + v[i].y; o.w = o.z + v[i].z;
            run = o.w + v[i].w;
            *(int4*)(base + idx) = o;
        } else {
            if (idx + 0 < N_NODES) { base[idx+0] = run; run += v[i].x; }
            if (idx + 1 < N_NODES) { base[idx+1] = run; run += v[i].y; }
            if (idx + 2 < N_NODES) { base[idx+2] = run; run += v[i].z; }
            if (idx + 3 < N_NODES) { base[idx+3] = run; run += v[i].w; }
        }
    }
    if (t == 1023) base[N_NODES] = run;
}

// ---------------------------------------------------------------------------
// K_sub: cur2[d][et] = base[d] + exclusive-prefix_et(hist2[d][.])
__global__ __launch_bounds__(256)
void k_sub(const int* __restrict__ hist2, const int* __restrict__ base,
           int* __restrict__ cur2) {
    int d = blockIdx.x * 256 + threadIdx.x;
    if (d < N_NODES) {
        int4 a = *(const int4*)(hist2 + d * 8);
        int4 b = *(const int4*)(hist2 + d * 8 + 4);
        int run = base[d];
        int4 oa, ob;
        oa.x = run; run += a.x;
        oa.y = run; run += a.y;
        oa.z = run; run += a.z;
        oa.w = run; run += a.w;
        ob.x = run; run += b.x;
        ob.y = run; run += b.y;
        ob.z = run; run += b.z;
        ob.w = run;
        *(int4*)(cur2 + d * 8)     = oa;
        *(int4*)(cur2 + d * 8 + 4) = ob;
    }
}

// ---------------------------------------------------------------------------
// K_scatter: bucket edges by (dst, et). recs = {(src<<3)|et, bits(norm)}.
__global__ __launch_bounds__(256)
void k_scatter(const int* __restrict__ src, const int* __restrict__ dst,
               const int* __restrict__ et, const float* __restrict__ norm,
               int* __restrict__ cur2, uint2* __restrict__ recs) {
    int e = blockIdx.x * 256 + threadIdx.x;
    if (e >= N_EDGES) return;
    int d = dst[e], r = et[e];
    int pos = atomicAdd(&cur2[d * 8 + r], 1);
    uint2 rc;
    rc.x = ((unsigned)src[e] << 3) | (unsigned)r;
    rc.y = __float_as_uint(norm[e]);
    recs[pos] = rc;
}

// ---------------------------------------------------------------------------
// K_mega: 32 nodes/block, 512 thr (8 waves), LDS ~82.4 KB -> 1 block/CU.
//  P1b gather: 32 groups x 1 node, (dst,et)-sorted runs -> reg acc, flush/et.
//  P2 MFMA: wave wv owns col-tile ct=wv (16 cols) x BOTH row tiles -> B loaded
//     ONCE per (ks) as a coalesced 1KB fragment-ordered segment (WcatF).
//  P3 MFMA: same decomposition with fwF. P4 LayerNorm.
__global__ __launch_bounds__(512)
void k_mega(const bf16* __restrict__ hb16, const uint2* __restrict__ recs,
            const int* __restrict__ base, const bf16* __restrict__ WcatF,
            const float* __restrict__ bias,
            const bf16* __restrict__ fwF, const float* __restrict__ ffn_b,
            const float* __restrict__ ln_g, const float* __restrict__ ln_b,
            float* __restrict__ out) {
    __shared__ __align__(16) char Tf[TN * TROW];    // 74,240 B bf16 Tcat
    __shared__ __align__(16) char hnb[TN * 256];    // 8 KB bf16 swz
    char* aggy = Tf;                                // 16 KB alias for P3/P4
    const int t = threadIdx.x, wv = t >> 6, l = t & 63;
    const int n0 = blockIdx.x * TN;

    // ---- P0: zero relation region [0, 2048)B of each row ----
    {
        const f32x4 z4{0.f, 0.f, 0.f, 0.f};
#pragma unroll
        for (int u = t; u < TN * 128; u += 512) {
            int row = u >> 7, off = (u & 127) * 16;
            *(f32x4*)(Tf + row * TROW + off) = z4;
        }
    }
    __syncthreads();

    const int grp = t >> 4, c = t & 15;
    const int gbase = l & 48;            // group's base lane within wave
    const int n = n0 + grp;
    const long long nc = (n < N_NODES) ? n : (N_NODES - 1);
    const int rowb = grp * TROW;

    // ---- P1a: self-loop slice (bytes 2048..2304): direct bf16 copy ----
    *(bf16x8*)(Tf + rowb + 2048 + c * 16) =
        *(const bf16x8*)(hb16 + nc * DIM + c * 8);

    // ---- P1b: gather (sorted runs -> reg acc + flush per et) ----
    if (n < N_NODES) {
        const int b0 = base[n], b1 = base[n + 1];
        float acc[8];
#pragma unroll
        for (int q = 0; q < 8; ++q) acc[q] = 0.f;
        int cur_et = -1;

        auto flush = [&]() {
            frag_u o;
#pragma unroll
            for (int q = 0; q < 8; ++q) o.e[q] = __float2bfloat16(acc[q]);
            *(bf16x8*)(Tf + rowb + cur_et * 256 + c * 16) = o.v;
#pragma unroll
            for (int q = 0; q < 8; ++q) acc[q] = 0.f;
        };

        for (int eb = b0; eb < b1; eb += 4) {
            const int rem = b1 - eb;
            uint2 md = (c < 4 && c < rem) ? recs[eb + c] : uint2{0u, 0u};
            const unsigned sk0 = (unsigned)__shfl((int)md.x, gbase + 0);
            const unsigned sk1 = (unsigned)__shfl((int)md.x, gbase + 1);
            const unsigned sk2 = (unsigned)__shfl((int)md.x, gbase + 2);
            const unsigned sk3 = (unsigned)__shfl((int)md.x, gbase + 3);
            const float wk0 = __uint_as_float(__shfl((int)md.y, gbase + 0));
            const float wk1 = __uint_as_float(__shfl((int)md.y, gbase + 1));
            const float wk2 = __uint_as_float(__shfl((int)md.y, gbase + 2));
            const float wk3 = __uint_as_float(__shfl((int)md.y, gbase + 3));
            frag_u f0, f1, f2, f3;   // 4 independent L2 loads in flight
            f0.v = *(const bf16x8*)(hb16 + (long long)(sk0 >> 3) * DIM + c * 8);
            f1.v = *(const bf16x8*)(hb16 + (long long)(sk1 >> 3) * DIM + c * 8);
            f2.v = *(const bf16x8*)(hb16 + (long long)(sk2 >> 3) * DIM + c * 8);
            f3.v = *(const bf16x8*)(hb16 + (long long)(sk3 >> 3) * DIM + c * 8);

#define STEP(K, SK, WK, FK)                                              \
            if (K < rem) {                                               \
                const int et_ = (int)(SK & 7u);                          \
                if (et_ != cur_et) {                                     \
                    if (cur_et >= 0) flush();                            \
                    cur_et = et_;                                        \
                }                                                        \
                _Pragma("unroll")                                        \
                for (int q = 0; q < 8; ++q)                              \
                    acc[q] = fmaf(WK, __bfloat162float(FK.e[q]), acc[q]);\
            }
            STEP(0, sk0, wk0, f0)
            STEP(1, sk1, wk1, f1)
            STEP(2, sk2, wk2, f2)
            STEP(3, sk3, wk3, f3)
#undef STEP
        }
        if (cur_et >= 0) flush();
    }
    __syncthreads();

    // ---- P2: hn = relu(Tcat @ Wcat + bias), K=1152.
    //      Wave wv: col tile ct=wv (cols wv*16..+15), rows 0..31 (2 tiles). ----
    const int lrow = l & 15, kgrp = l >> 4;
    const int ct = wv;
    {
        f32x4 acc1[2];
#pragma unroll
        for (int rt = 0; rt < 2; ++rt) acc1[rt] = f32x4{0.f, 0.f, 0.f, 0.f};
        const bf16* Bf = WcatF + (long long)ct * NKS * 512;
#pragma unroll 4
        for (int ks = 0; ks < NKS; ++ks) {
            frag_u b;
            b.v = *(const bf16x8*)(Bf + ks * 512 + l * 8);   // coalesced 1KB
#pragma unroll
            for (int rt = 0; rt < 2; ++rt) {
                frag_u a;
                a.v = *(const bf16x8*)(Tf + (rt * 16 + lrow) * TROW +
                                       ks * 64 + kgrp * 16);
                acc1[rt] = __builtin_amdgcn_mfma_f32_16x16x32_bf16(
                    b.v, a.v, acc1[rt], 0, 0, 0);
            }
        }
        const int col = ct * 16 + kgrp * 4;
        f32x4 bi = *(const f32x4*)(bias + col);
#pragma unroll
        for (int rt = 0; rt < 2; ++rt) {
            int row = rt * 16 + lrow;
            pack4_u p;
#pragma unroll
            for (int j = 0; j < 4; ++j)
                p.b[j] = __float2bfloat16(fmaxf(acc1[rt][j] + bi[j], 0.f));
            *(unsigned long long*)(hnb + ((row * 256 + col * 2) ^ swzb(row))) = p.ll;
        }
    }
    __syncthreads();

    // ---- P3: y = hn @ ffn_w^T + ffn_b + h, K=128 -> aggy (aliases Tf) ----
    {
        f32x4 acc2[2];
#pragma unroll
        for (int rt = 0; rt < 2; ++rt) acc2[rt] = f32x4{0.f, 0.f, 0.f, 0.f};
        const bf16* Bf = fwF + (long long)ct * 4 * 512;
#pragma unroll
        for (int ks = 0; ks < 4; ++ks) {
            frag_u b;
            b.v = *(const bf16x8*)(Bf + ks * 512 + l * 8);   // coalesced 1KB
#pragma unroll
            for (int rt = 0; rt < 2; ++rt) {
                int row = rt * 16 + lrow;
                frag_u a;
                a.v = *(const bf16x8*)(hnb +
                        ((row * 256 + ks * 64 + kgrp * 16) ^ swzb(row)));
                acc2[rt] = __builtin_amdgcn_mfma_f32_16x16x32_bf16(
                    b.v, a.v, acc2[rt], 0, 0, 0);
            }
        }
        const int col = ct * 16 + kgrp * 4;
        f32x4 fb = *(const f32x4*)(ffn_b + col);
#pragma unroll
        for (int rt = 0; rt < 2; ++rt) {
            int row = rt * 16 + lrow;
            const long long gr = (n0 + row < N_NODES) ? (n0 + row) : (N_NODES - 1);
            pack4_u hp;
            hp.ll = *(const unsigned long long*)(hb16 + gr * DIM + col);
            f32x4 y;
#pragma unroll
            for (int j = 0; j < 4; ++j)
                y[j] = acc2[rt][j] + fb[j] + __bfloat162float(hp.b[j]);
            *(f32x4*)(aggy + row * 512 + ((col * 4) ^ swzy(row))) = y;
        }
    }
    __syncthreads();

    // ---- P4: LayerNorm. 8 waves x 4 rows. Addr swizzled; col = PRE-swz 2l. ----
#pragma unroll 1
    for (int jr = 0; jr < 4; ++jr) {
        const int row = wv * 4 + jr;
        const int nn = n0 + row;
        const int x = swzy(row);
        float2 yv = *(const float2*)(aggy + row * 512 + ((l * 8) ^ x));
        const int col = l * 2;
        float s = yv.x + yv.y, s2 = yv.x * yv.x + yv.y * yv.y;
#pragma unroll
        for (int m = 1; m < 64; m <<= 1) {
            s  += __shfl_xor(s, m);
            s2 += __shfl_xor(s2, m);
        }
        if (nn < N_NODES) {
            float mu  = s * (1.f / DIM);
            float var = s2 * (1.f / DIM) - mu * mu;
            float inv = rsqrtf(var + 1e-8f);
            float2 gv = *(const float2*)(ln_g + col);
            float2 bv = *(const float2*)(ln_b + col);
            float2 o2{(yv.x - mu) * inv * gv.x + bv.x,
                      (yv.y - mu) * inv * gv.y + bv.y};
            *(float2*)(out + (long long)nn * DIM + col) = o2;
        }
    }
}

// ---------------------------------------------------------------------------
extern "C" void kernel_launch(void* const* d_in, const int* in_sizes, int n_in,
                              void* d_out, int out_size, void* d_ws, size_t ws_size,
                              hipStream_t stream) {
    const float* h      = (const float*)d_in[0];
    const float* V      = (const float*)d_in[1];
    const float* w_comp = (const float*)d_in[2];
    const float* loop_w = (const float*)d_in[3];
    const float* bias   = (const float*)d_in[4];
    const float* ffn_w  = (const float*)d_in[5];
    const float* ffn_b  = (const float*)d_in[6];
    const float* ln_g   = (const float*)d_in[7];
    const float* ln_b   = (const float*)d_in[8];
    const float* norm   = (const float*)d_in[9];
    const int*   src    = (const int*)d_in[10];
    const int*   dst    = (const int*)d_in[11];
    const int*   etype  = (const int*)d_in[12];
    float* out = (float*)d_out;

    if (ws_size < (size_t)WS_NEEDED) return;

    char* ws = (char*)d_ws;
    bf16*  hb16  = (bf16*)(ws + HB16_OFF);
    uint2* recs  = (uint2*)(ws + RECS_OFF);
    int*   hist2 = (int*)(ws + HIST_OFF);
    int*   cur2  = (int*)(ws + CUR2_OFF);
    int*   deg   = (int*)(ws + DEG_OFF);
    int*   base  = (int*)(ws + BASE_OFF);
    bf16*  WcatF = (bf16*)(ws + WCAT_OFF);
    bf16*  fwF   = (bf16*)(ws + FWF_OFF);

    hipMemsetAsync(hist2, 0, N_NODES * NREL * sizeof(int), stream);

    k_prep<<<dim3(3125), dim3(256), 0, stream>>>(
        h, V, w_comp, loop_w, ffn_w, dst, etype, hb16, WcatF, fwF, hist2);

    k_deg<<<dim3((N_NODES + 255) / 256), dim3(256), 0, stream>>>(hist2, deg);
    k_scan<<<dim3(1), dim3(1024), 0, stream>>>(deg, base);
    k_sub<<<dim3((N_NODES + 255) / 256), dim3(256), 0, stream>>>(hist2, base, cur2);
    k_scatter<<<dim3((N_EDGES + 255) / 256), dim3(256), 0, stream>>>(
        src, dst, etype, norm, cur2, recs);

    k_mega<<<dim3((N_NODES + TN - 1) / TN), dim3(512), 0, stream>>>(
        hb16, recs, base, WcatF, bias, fwF, ffn_b, ln_g, ln_b, out);
}

// Round 15
// 159.247 us; speedup vs baseline: 2.8234x; 1.0058x over previous
//
#include <hip/hip_runtime.h>
#include <hip/hip_bf16.h>

#define N_NODES 50000
#define N_EDGES 400000
#define DIM     128
#define NREL    8
#define NBASES  4
#define KCAT    1152            // 8*128 relation slices + 128 self-loop
#define NKS     36              // KCAT/32
#define TN      32              // nodes per mega-block
#define TROW    2320            // Tcat bf16 row stride bytes (145*16B, 145 odd -> spread)

typedef __hip_bfloat16 bf16;

typedef __bf16 bf16x8 __attribute__((ext_vector_type(8)));
typedef float  f32x4  __attribute__((ext_vector_type(4)));

union frag_u { bf16x8 v; bf16 e[8]; };
union pack4_u { unsigned long long ll; bf16 b[4]; };

// ---- workspace layout (bytes) ----
// hb16  bf16 [N][D]          : 12,800,000
// recs  uint2 [E]            :  3,200,000  ((dst,et)-sorted; key=(src<<3)|et)
// hist2 int [N*8]            :  1,600,000
// cur2  int [N*8]            :  1,600,000
// deg   int [N] pad          :    200,064
// base  int [N+1] pad        :    200,064
// WcatF bf16 [8][36][64][8]  :    294,912  (fragment-ordered stacked weights)
// fwF   bf16 [8][4][64][8]   :     32,768  (fragment-ordered ffn_w)
#define HB16_OFF  0LL
#define RECS_OFF  12800000LL
#define HIST_OFF  16000000LL
#define CUR2_OFF  17600000LL
#define DEG_OFF   19200000LL
#define BASE_OFF  19400064LL
#define WCAT_OFF  19600128LL
#define FWF_OFF   19895040LL
#define WS_NEEDED 19927808LL

__device__ __forceinline__ int swzb(int row) { return (row & 15) << 4; }  // 256B rows
__device__ __forceinline__ int swzy(int row) { return (row & 31) << 4; }  // 512B rows

// ---------------------------------------------------------------------------
// K_prep: hb16 = bf16(h); hist2[(dst,et)]++; WcatF/fwF in FRAGMENT ORDER:
//   WcatF element (ct,ks,l,j) = Wcat^T[ct*16+(l&15)][ks*32+(l>>4)*8+j]
__global__ __launch_bounds__(256)
void k_prep(const float* __restrict__ h, const float* __restrict__ V,
            const float* __restrict__ wc,
            const float* __restrict__ loop_w, const float* __restrict__ ffn_w,
            const int* __restrict__ dst, const int* __restrict__ et,
            bf16* __restrict__ hb, bf16* __restrict__ WcatF,
            bf16* __restrict__ fwF, int* __restrict__ hist2) {
    int p = blockIdx.x * 256 + threadIdx.x;
    if (p < N_NODES * DIM / 8) {
        const float* s = h + (long long)p * 8;
        f32x4 lo = *(const f32x4*)s, hi = *(const f32x4*)(s + 4);
        frag_u o;
#pragma unroll
        for (int j = 0; j < 4; ++j) {
            o.e[j]     = __float2bfloat16(lo[j]);
            o.e[4 + j] = __float2bfloat16(hi[j]);
        }
        *(bf16x8*)(hb + (long long)p * 8) = o.v;
    }
    if (p < N_EDGES) atomicAdd(&hist2[dst[p] * 8 + et[p]], 1);
    if (p < 8 * NKS * 64 * 8) {            // 147456 WcatF elements
        int idx = p;
        int j = idx & 7; idx >>= 3;
        int l = idx & 63; idx >>= 6;
        int ks = idx % NKS, ct = idx / NKS;
        int col = ct * 16 + (l & 15);
        int k = ks * 32 + (l >> 4) * 8 + j;
        float val;
        if (k < 1024) {
            int r = k >> 7, i = k & 127;
            val = 0.f;
#pragma unroll
            for (int b = 0; b < NBASES; ++b)
                val += wc[r * NBASES + b] * V[(b << 14) + i * DIM + col];
        } else {
            val = loop_w[(k - 1024) * DIM + col];
        }
        WcatF[p] = __float2bfloat16(val);
    }
    if (p < 8 * 4 * 64 * 8) {              // 16384 fwF elements
        int idx = p;
        int j = idx & 7; idx >>= 3;
        int l = idx & 63; idx >>= 6;
        int ks = idx & 3, ct = idx >> 2;
        int col = ct * 16 + (l & 15);
        int k = ks * 32 + (l >> 4) * 8 + j;
        fwF[p] = __float2bfloat16(ffn_w[col * DIM + k]);   // ffn_w[o][i]
    }
}

// ---------------------------------------------------------------------------
// K_deg: deg[d] = sum_et hist2[d][et]
__global__ __launch_bounds__(256)
void k_deg(const int* __restrict__ hist2, int* __restrict__ deg) {
    int d = blockIdx.x * 256 + threadIdx.x;
    if (d < N_NODES) {
        int4 a = *(const int4*)(hist2 + d * 8);
        int4 b = *(const int4*)(hist2 + d * 8 + 4);
        deg[d] = a.x + a.y + a.z + a.w + b.x + b.y + b.z + b.w;
    }
}

// ---------------------------------------------------------------------------
// K_scan: exclusive prefix sum of deg -> base. 1 block, 1024 thr.
#define SCAN_V 13
__global__ __launch_bounds__(1024)
void k_scan(const int* __restrict__ deg, int* __restrict__ base) {
    __shared__ int wsum[16];
    const int t = threadIdx.x, lane = t & 63, wv = t >> 6;
    const int i0 = t * (SCAN_V * 4);
    int4 v[SCAN_V];
#pragma unroll
    for (int i = 0; i < SCAN_V; ++i) {
        int idx = i0 + i * 4;
        if (idx + 3 < N_NODES) v[i] = *(const int4*)(deg + idx);
        else {
            v[i].x = (idx + 0 < N_NODES) ? deg[idx + 0] : 0;
            v[i].y = (idx + 1 < N_NODES) ? deg[idx + 1] : 0;
            v[i].z = (idx + 2 < N_NODES) ? deg[idx + 2] : 0;
            v[i].w = (idx + 3 < N_NODES) ? deg[idx + 3] : 0;
        }
    }
    int s = 0;
#pragma unroll
    for (int i = 0; i < SCAN_V; ++i) s += v[i].x + v[i].y + v[i].z + v[i].w;
    int inc = s;
#pragma unroll
    for (int m = 1; m < 64; m <<= 1) {
        int u = __shfl_up(inc, m);
        if (lane >= m) inc += u;
    }
    if (lane == 63) wsum[wv] = inc;
    __syncthreads();
    if (t < 16) {
        int w = wsum[t];
        int winc = w;
#pragma unroll
        for (int m = 1; m < 16; m <<= 1) {
            int u = __shfl_up(winc, m);
            if (t >= m) winc += u;
        }
        wsum[t] = winc - w;
    }
    __syncthreads();
    int run = wsum[wv] + (inc - s);
#pragma unroll
    for (int i = 0; i < SCAN_V; ++i) {
        int idx = i0 + i * 4;
        if (idx + 3 < N_NODES) {
            int4 o;
            o.x = run; o.y = o.x + v[i].x; o.z = o.y + v[i].y; o.w = o.z + v[i].z;
            run = o.w + v[i].w;
            *(int4*)(base + idx) = o;
        } else {
            if (idx + 0 < N_NODES) { base[idx+0] = run; run += v[i].x; }
            if (idx + 1 < N_NODES) { base[idx+1] = run; run += v[i].y; }
            if (idx + 2 < N_NODES) { base[idx+2] = run; run += v[i].z; }
            if (idx + 3 < N_NODES) { base[idx+3] = run; run += v[i].w; }
        }
    }
    if (t == 1023) base[N_NODES] = run;
}

// ---------------------------------------------------------------------------
// K_sub: cur2[d][et] = base[d] + exclusive-prefix_et(hist2[d][.])
__global__ __launch_bounds__(256)
void k_sub(const int* __restrict__ hist2, const int* __restrict__ base,
           int* __restrict__ cur2) {
    int d = blockIdx.x * 256 + threadIdx.x;
    if (d < N_NODES) {
        int4 a = *(const int4*)(hist2 + d * 8);
        int4 b = *(const int4*)(hist2 + d * 8 + 4);
        int run = base[d];
        int4 oa, ob;
        oa.x = run; run += a.x;
        oa.y = run; run += a.y;
        oa.z = run; run += a.z;
        oa.w = run; run += a.w;
        ob.x = run; run += b.x;
        ob.y = run; run += b.y;
        ob.z = run; run += b.z;
        ob.w = run;
        *(int4*)(cur2 + d * 8)     = oa;
        *(int4*)(cur2 + d * 8 + 4) = ob;
    }
}

// ---------------------------------------------------------------------------
// K_scatter: bucket edges by (dst, et). recs = {(src<<3)|et, bits(norm)}.
__global__ __launch_bounds__(256)
void k_scatter(const int* __restrict__ src, const int* __restrict__ dst,
               const int* __restrict__ et, const float* __restrict__ norm,
               int* __restrict__ cur2, uint2* __restrict__ recs) {
    int e = blockIdx.x * 256 + threadIdx.x;
    if (e >= N_EDGES) return;
    int d = dst[e], r = et[e];
    int pos = atomicAdd(&cur2[d * 8 + r], 1);
    uint2 rc;
    rc.x = ((unsigned)src[e] << 3) | (unsigned)r;
    rc.y = __float_as_uint(norm[e]);
    recs[pos] = rc;
}

// ---------------------------------------------------------------------------
// K_mega: 32 nodes/block, 512 thr (8 waves), LDS ~82.4 KB -> 1 block/CU.
//  P1b gather: 32 groups x 1 node, (dst,et)-sorted runs -> reg acc, flush/et.
//  P2 MFMA: wave wv owns col-tile ct=wv (16 cols) x BOTH row tiles -> B loaded
//     ONCE per (ks) as a coalesced 1KB fragment-ordered segment (WcatF).
//  P3 MFMA: same decomposition with fwF. P4 LayerNorm.
__global__ __launch_bounds__(512)
void k_mega(const bf16* __restrict__ hb16, const uint2* __restrict__ recs,
            const int* __restrict__ base, const bf16* __restrict__ WcatF,
            const float* __restrict__ bias,
            const bf16* __restrict__ fwF, const float* __restrict__ ffn_b,
            const float* __restrict__ ln_g, const float* __restrict__ ln_b,
            float* __restrict__ out) {
    __shared__ __align__(16) char Tf[TN * TROW];    // 74,240 B bf16 Tcat
    __shared__ __align__(16) char hnb[TN * 256];    // 8 KB bf16 swz
    char* aggy = Tf;                                // 16 KB alias for P3/P4
    const int t = threadIdx.x, wv = t >> 6, l = t & 63;
    const int n0 = blockIdx.x * TN;

    // ---- P0: zero relation region [0, 2048)B of each row ----
    {
        const f32x4 z4{0.f, 0.f, 0.f, 0.f};
#pragma unroll
        for (int u = t; u < TN * 128; u += 512) {
            int row = u >> 7, off = (u & 127) * 16;
            *(f32x4*)(Tf + row * TROW + off) = z4;
        }
    }
    __syncthreads();

    const int grp = t >> 4, c = t & 15;
    const int gbase = l & 48;            // group's base lane within wave
    const int n = n0 + grp;
    const long long nc = (n < N_NODES) ? n : (N_NODES - 1);
    const int rowb = grp * TROW;

    // ---- P1a: self-loop slice (bytes 2048..2304): direct bf16 copy ----
    *(bf16x8*)(Tf + rowb + 2048 + c * 16) =
        *(const bf16x8*)(hb16 + nc * DIM + c * 8);

    // ---- P1b: gather (sorted runs -> reg acc + flush per et) ----
    if (n < N_NODES) {
        const int b0 = base[n], b1 = base[n + 1];
        float acc[8];
#pragma unroll
        for (int q = 0; q < 8; ++q) acc[q] = 0.f;
        int cur_et = -1;

        auto flush = [&]() {
            frag_u o;
#pragma unroll
            for (int q = 0; q < 8; ++q) o.e[q] = __float2bfloat16(acc[q]);
            *(bf16x8*)(Tf + rowb + cur_et * 256 + c * 16) = o.v;
#pragma unroll
            for (int q = 0; q < 8; ++q) acc[q] = 0.f;
        };

        for (int eb = b0; eb < b1; eb += 4) {
            const int rem = b1 - eb;
            uint2 md = (c < 4 && c < rem) ? recs[eb + c] : uint2{0u, 0u};
            const unsigned sk0 = (unsigned)__shfl((int)md.x, gbase + 0);
            const unsigned sk1 = (unsigned)__shfl((int)md.x, gbase + 1);
            const unsigned sk2 = (unsigned)__shfl((int)md.x, gbase + 2);
            const unsigned sk3 = (unsigned)__shfl((int)md.x, gbase + 3);
            const float wk0 = __uint_as_float(__shfl((int)md.y, gbase + 0));
            const float wk1 = __uint_as_float(__shfl((int)md.y, gbase + 1));
            const float wk2 = __uint_as_float(__shfl((int)md.y, gbase + 2));
            const float wk3 = __uint_as_float(__shfl((int)md.y, gbase + 3));
            frag_u f0, f1, f2, f3;   // 4 independent L2 loads in flight
            f0.v = *(const bf16x8*)(hb16 + (long long)(sk0 >> 3) * DIM + c * 8);
            f1.v = *(const bf16x8*)(hb16 + (long long)(sk1 >> 3) * DIM + c * 8);
            f2.v = *(const bf16x8*)(hb16 + (long long)(sk2 >> 3) * DIM + c * 8);
            f3.v = *(const bf16x8*)(hb16 + (long long)(sk3 >> 3) * DIM + c * 8);

#define STEP(K, SK, WK, FK)                                              \
            if (K < rem) {                                               \
                const int et_ = (int)(SK & 7u);                          \
                if (et_ != cur_et) {                                     \
                    if (cur_et >= 0) flush();                            \
                    cur_et = et_;                                        \
                }                                                        \
                _Pragma("unroll")                                        \
                for (int q = 0; q < 8; ++q)                              \
                    acc[q] = fmaf(WK, __bfloat162float(FK.e[q]), acc[q]);\
            }
            STEP(0, sk0, wk0, f0)
            STEP(1, sk1, wk1, f1)
            STEP(2, sk2, wk2, f2)
            STEP(3, sk3, wk3, f3)
#undef STEP
        }
        if (cur_et >= 0) flush();
    }
    __syncthreads();

    // ---- P2: hn = relu(Tcat @ Wcat + bias), K=1152.
    //      Wave wv: col tile ct=wv (cols wv*16..+15), rows 0..31 (2 tiles). ----
    const int lrow = l & 15, kgrp = l >> 4;
    const int ct = wv;
    {
        f32x4 acc1[2];
#pragma unroll
        for (int rt = 0; rt < 2; ++rt) acc1[rt] = f32x4{0.f, 0.f, 0.f, 0.f};
        const bf16* Bf = WcatF + (long long)ct * NKS * 512;
#pragma unroll 4
        for (int ks = 0; ks < NKS; ++ks) {
            frag_u b;
            b.v = *(const bf16x8*)(Bf + ks * 512 + l * 8);   // coalesced 1KB
#pragma unroll
            for (int rt = 0; rt < 2; ++rt) {
                frag_u a;
                a.v = *(const bf16x8*)(Tf + (rt * 16 + lrow) * TROW +
                                       ks * 64 + kgrp * 16);
                acc1[rt] = __builtin_amdgcn_mfma_f32_16x16x32_bf16(
                    b.v, a.v, acc1[rt], 0, 0, 0);
            }
        }
        const int col = ct * 16 + kgrp * 4;
        f32x4 bi = *(const f32x4*)(bias + col);
#pragma unroll
        for (int rt = 0; rt < 2; ++rt) {
            int row = rt * 16 + lrow;
            pack4_u p;
#pragma unroll
            for (int j = 0; j < 4; ++j)
                p.b[j] = __float2bfloat16(fmaxf(acc1[rt][j] + bi[j], 0.f));
            *(unsigned long long*)(hnb + ((row * 256 + col * 2) ^ swzb(row))) = p.ll;
        }
    }
    __syncthreads();

    // ---- P3: y = hn @ ffn_w^T + ffn_b + h, K=128 -> aggy (aliases Tf) ----
    {
        f32x4 acc2[2];
#pragma unroll
        for (int rt = 0; rt < 2; ++rt) acc2[rt] = f32x4{0.f, 0.f, 0.f, 0.f};
        const bf16* Bf = fwF + (long long)ct * 4 * 512;
#pragma unroll
        for (int ks = 0; ks < 4; ++ks) {
            frag_u b;
            b.v = *(const bf16x8*)(Bf + ks * 512 + l * 8);   // coalesced 1KB
#pragma unroll
            for (int rt = 0; rt < 2; ++rt) {
                int row = rt * 16 + lrow;
                frag_u a;
                a.v = *(const bf16x8*)(hnb +
                        ((row * 256 + ks * 64 + kgrp * 16) ^ swzb(row)));
                acc2[rt] = __builtin_amdgcn_mfma_f32_16x16x32_bf16(
                    b.v, a.v, acc2[rt], 0, 0, 0);
            }
        }
        const int col = ct * 16 + kgrp * 4;
        f32x4 fb = *(const f32x4*)(ffn_b + col);
#pragma unroll
        for (int rt = 0; rt < 2; ++rt) {
            int row = rt * 16 + lrow;
            const long long gr = (n0 + row < N_NODES) ? (n0 + row) : (N_NODES - 1);
            pack4_u hp;
            hp.ll = *(const unsigned long long*)(hb16 + gr * DIM + col);
            f32x4 y;
#pragma unroll
            for (int j = 0; j < 4; ++j)
                y[j] = acc2[rt][j] + fb[j] + __bfloat162float(hp.b[j]);
            *(f32x4*)(aggy + row * 512 + ((col * 4) ^ swzy(row))) = y;
        }
    }
    __syncthreads();

    // ---- P4: LayerNorm. 8 waves x 4 rows. Addr swizzled; col = PRE-swz 2l. ----
#pragma unroll 1
    for (int jr = 0; jr < 4; ++jr) {
        const int row = wv * 4 + jr;
        const int nn = n0 + row;
        const int x = swzy(row);
        float2 yv = *(const float2*)(aggy + row * 512 + ((l * 8) ^ x));
        const int col = l * 2;
        float s = yv.x + yv.y, s2 = yv.x * yv.x + yv.y * yv.y;
#pragma unroll
        for (int m = 1; m < 64; m <<= 1) {
            s  += __shfl_xor(s, m);
            s2 += __shfl_xor(s2, m);
        }
        if (nn < N_NODES) {
            float mu  = s * (1.f / DIM);
            float var = s2 * (1.f / DIM) - mu * mu;
            float inv = rsqrtf(var + 1e-8f);
            float2 gv = *(const float2*)(ln_g + col);
            float2 bv = *(const float2*)(ln_b + col);
            float2 o2{(yv.x - mu) * inv * gv.x + bv.x,
                      (yv.y - mu) * inv * gv.y + bv.y};
            *(float2*)(out + (long long)nn * DIM + col) = o2;
        }
    }
}

// ---------------------------------------------------------------------------
extern "C" void kernel_launch(void* const* d_in, const int* in_sizes, int n_in,
                              void* d_out, int out_size, void* d_ws, size_t ws_size,
                              hipStream_t stream) {
    const float* h      = (const float*)d_in[0];
    const float* V      = (const float*)d_in[1];
    const float* w_comp = (const float*)d_in[2];
    const float* loop_w = (const float*)d_in[3];
    const float* bias   = (const float*)d_in[4];
    const float* ffn_w  = (const float*)d_in[5];
    const float* ffn_b  = (const float*)d_in[6];
    const float* ln_g   = (const float*)d_in[7];
    const float* ln_b   = (const float*)d_in[8];
    const float* norm   = (const float*)d_in[9];
    const int*   src    = (const int*)d_in[10];
    const int*   dst    = (const int*)d_in[11];
    const int*   etype  = (const int*)d_in[12];
    float* out = (float*)d_out;

    if (ws_size < (size_t)WS_NEEDED) return;

    char* ws = (char*)d_ws;
    bf16*  hb16  = (bf16*)(ws + HB16_OFF);
    uint2* recs  = (uint2*)(ws + RECS_OFF);
    int*   hist2 = (int*)(ws + HIST_OFF);
    int*   cur2  = (int*)(ws + CUR2_OFF);
    int*   deg   = (int*)(ws + DEG_OFF);
    int*   base  = (int*)(ws + BASE_OFF);
    bf16*  WcatF = (bf16*)(ws + WCAT_OFF);
    bf16*  fwF   = (bf16*)(ws + FWF_OFF);

    hipMemsetAsync(hist2, 0, N_NODES * NREL * sizeof(int), stream);

    k_prep<<<dim3(3125), dim3(256), 0, stream>>>(
        h, V, w_comp, loop_w, ffn_w, dst, etype, hb16, WcatF, fwF, hist2);

    k_deg<<<dim3((N_NODES + 255) / 256), dim3(256), 0, stream>>>(hist2, deg);
    k_scan<<<dim3(1), dim3(1024), 0, stream>>>(deg, base);
    k_sub<<<dim3((N_NODES + 255) / 256), dim3(256), 0, stream>>>(hist2, base, cur2);
    k_scatter<<<dim3((N_EDGES + 255) / 256), dim3(256), 0, stream>>>(
        src, dst, etype, norm, cur2, recs);

    k_mega<<<dim3((N_NODES + TN - 1) / TN), dim3(512), 0, stream>>>(
        hb16, recs, base, WcatF, bias, fwF, ffn_b, ln_g, ln_b, out);
}

// Round 16
// 149.097 us; speedup vs baseline: 3.0157x; 1.0681x over previous
//
#include <hip/hip_runtime.h>
#include <hip/hip_bf16.h>

#define N_NODES 50000
#define N_EDGES 400000
#define DIM     128
#define NREL    8
#define NBASES  4
#define KCAT    1152            // 8*128 relation slices + 128 self-loop
#define NKS     36              // KCAT/32
#define TN      16              // nodes per mega-block (R10's proven shape)
#define TROW    2320            // Tcat bf16 row stride bytes (145*16B, odd -> spread)

typedef __hip_bfloat16 bf16;

typedef __bf16 bf16x8 __attribute__((ext_vector_type(8)));
typedef float  f32x4  __attribute__((ext_vector_type(4)));

union frag_u { bf16x8 v; bf16 e[8]; };
union pack4_u { unsigned long long ll; bf16 b[4]; };

// ---- workspace layout (bytes) ----
// hb16  bf16 [N][D]          : 12,800,000
// recs  uint2 [E]            :  3,200,000  ((dst,et)-sorted; key=(src<<3)|et)
// hist2 int [N*8]            :  1,600,000
// cur2  int [N*8]            :  1,600,000
// deg   int [N] pad          :    200,064
// base  int [N+1] pad        :    200,064
// WcatF bf16 [8][36][64][8]  :    294,912  (fragment-ordered stacked weights)
// fwF   bf16 [8][4][64][8]   :     32,768  (fragment-ordered ffn_w)
#define HB16_OFF  0LL
#define RECS_OFF  12800000LL
#define HIST_OFF  16000000LL
#define CUR2_OFF  17600000LL
#define DEG_OFF   19200000LL
#define BASE_OFF  19400064LL
#define WCAT_OFF  19600128LL
#define FWF_OFF   19895040LL
#define WS_NEEDED 19927808LL

__device__ __forceinline__ int swzb(int row) { return (row & 15) << 4; }  // 256B rows
__device__ __forceinline__ int swzy(int row) { return (row & 31) << 4; }  // 512B rows

// ---------------------------------------------------------------------------
// K_prep: hb16 = bf16(h); hist2[(dst,et)]++; WcatF/fwF in FRAGMENT ORDER:
//   WcatF element (ct,ks,l,j) = Wcat^T[ct*16+(l&15)][ks*32+(l>>4)*8+j]
__global__ __launch_bounds__(256)
void k_prep(const float* __restrict__ h, const float* __restrict__ V,
            const float* __restrict__ wc,
            const float* __restrict__ loop_w, const float* __restrict__ ffn_w,
            const int* __restrict__ dst, const int* __restrict__ et,
            bf16* __restrict__ hb, bf16* __restrict__ WcatF,
            bf16* __restrict__ fwF, int* __restrict__ hist2) {
    int p = blockIdx.x * 256 + threadIdx.x;
    if (p < N_NODES * DIM / 8) {
        const float* s = h + (long long)p * 8;
        f32x4 lo = *(const f32x4*)s, hi = *(const f32x4*)(s + 4);
        frag_u o;
#pragma unroll
        for (int j = 0; j < 4; ++j) {
            o.e[j]     = __float2bfloat16(lo[j]);
            o.e[4 + j] = __float2bfloat16(hi[j]);
        }
        *(bf16x8*)(hb + (long long)p * 8) = o.v;
    }
    if (p < N_EDGES) atomicAdd(&hist2[dst[p] * 8 + et[p]], 1);
    if (p < 8 * NKS * 64 * 8) {            // 147456 WcatF elements
        int idx = p;
        int j = idx & 7; idx >>= 3;
        int l = idx & 63; idx >>= 6;
        int ks = idx % NKS, ct = idx / NKS;
        int col = ct * 16 + (l & 15);
        int k = ks * 32 + (l >> 4) * 8 + j;
        float val;
        if (k < 1024) {
            int r = k >> 7, i = k & 127;
            val = 0.f;
#pragma unroll
            for (int b = 0; b < NBASES; ++b)
                val += wc[r * NBASES + b] * V[(b << 14) + i * DIM + col];
        } else {
            val = loop_w[(k - 1024) * DIM + col];
        }
        WcatF[p] = __float2bfloat16(val);
    }
    if (p < 8 * 4 * 64 * 8) {              // 16384 fwF elements
        int idx = p;
        int j = idx & 7; idx >>= 3;
        int l = idx & 63; idx >>= 6;
        int ks = idx & 3, ct = idx >> 2;
        int col = ct * 16 + (l & 15);
        int k = ks * 32 + (l >> 4) * 8 + j;
        fwF[p] = __float2bfloat16(ffn_w[col * DIM + k]);   // ffn_w[o][i]
    }
}

// ---------------------------------------------------------------------------
// K_deg: deg[d] = sum_et hist2[d][et]
__global__ __launch_bounds__(256)
void k_deg(const int* __restrict__ hist2, int* __restrict__ deg) {
    int d = blockIdx.x * 256 + threadIdx.x;
    if (d < N_NODES) {
        int4 a = *(const int4*)(hist2 + d * 8);
        int4 b = *(const int4*)(hist2 + d * 8 + 4);
        deg[d] = a.x + a.y + a.z + a.w + b.x + b.y + b.z + b.w;
    }
}

// ---------------------------------------------------------------------------
// K_scan: exclusive prefix sum of deg -> base. 1 block, 1024 thr.
#define SCAN_V 13
__global__ __launch_bounds__(1024)
void k_scan(const int* __restrict__ deg, int* __restrict__ base) {
    __shared__ int wsum[16];
    const int t = threadIdx.x, lane = t & 63, wv = t >> 6;
    const int i0 = t * (SCAN_V * 4);
    int4 v[SCAN_V];
#pragma unroll
    for (int i = 0; i < SCAN_V; ++i) {
        int idx = i0 + i * 4;
        if (idx + 3 < N_NODES) v[i] = *(const int4*)(deg + idx);
        else {
            v[i].x = (idx + 0 < N_NODES) ? deg[idx + 0] : 0;
            v[i].y = (idx + 1 < N_NODES) ? deg[idx + 1] : 0;
            v[i].z = (idx + 2 < N_NODES) ? deg[idx + 2] : 0;
            v[i].w = (idx + 3 < N_NODES) ? deg[idx + 3] : 0;
        }
    }
    int s = 0;
#pragma unroll
    for (int i = 0; i < SCAN_V; ++i) s += v[i].x + v[i].y + v[i].z + v[i].w;
    int inc = s;
#pragma unroll
    for (int m = 1; m < 64; m <<= 1) {
        int u = __shfl_up(inc, m);
        if (lane >= m) inc += u;
    }
    if (lane == 63) wsum[wv] = inc;
    __syncthreads();
    if (t < 16) {
        int w = wsum[t];
        int winc = w;
#pragma unroll
        for (int m = 1; m < 16; m <<= 1) {
            int u = __shfl_up(winc, m);
            if (t >= m) winc += u;
        }
        wsum[t] = winc - w;
    }
    __syncthreads();
    int run = wsum[wv] + (inc - s);
#pragma unroll
    for (int i = 0; i < SCAN_V; ++i) {
        int idx = i0 + i * 4;
        if (idx + 3 < N_NODES) {
            int4 o;
            o.x = run; o.y = o.x + v[i].x; o.z = o.y + v[i].y; o.w = o.z + v[i].z;
            run = o.w + v[i].w;
            *(int4*)(base + idx) = o;
        } else {
            if (idx + 0 < N_NODES) { base[idx+0] = run; run += v[i].x; }
            if (idx + 1 < N_NODES) { base[idx+1] = run; run += v[i].y; }
            if (idx + 2 < N_NODES) { base[idx+2] = run; run += v[i].z; }
            if (idx + 3 < N_NODES) { base[idx+3] = run; run += v[i].w; }
        }
    }
    if (t == 1023) base[N_NODES] = run;
}

// ---------------------------------------------------------------------------
// K_sub: cur2[d][et] = base[d] + exclusive-prefix_et(hist2[d][.])
__global__ __launch_bounds__(256)
void k_sub(const int* __restrict__ hist2, const int* __restrict__ base,
           int* __restrict__ cur2) {
    int d = blockIdx.x * 256 + threadIdx.x;
    if (d < N_NODES) {
        int4 a = *(const int4*)(hist2 + d * 8);
        int4 b = *(const int4*)(hist2 + d * 8 + 4);
        int run = base[d];
        int4 oa, ob;
        oa.x = run; run += a.x;
        oa.y = run; run += a.y;
        oa.z = run; run += a.z;
        oa.w = run; run += a.w;
        ob.x = run; run += b.x;
        ob.y = run; run += b.y;
        ob.z = run; run += b.z;
        ob.w = run;
        *(int4*)(cur2 + d * 8)     = oa;
        *(int4*)(cur2 + d * 8 + 4) = ob;
    }
}

// ---------------------------------------------------------------------------
// K_scatter: bucket edges by (dst, et). recs = {(src<<3)|et, bits(norm)}.
__global__ __launch_bounds__(256)
void k_scatter(const int* __restrict__ src, const int* __restrict__ dst,
               const int* __restrict__ et, const float* __restrict__ norm,
               int* __restrict__ cur2, uint2* __restrict__ recs) {
    int e = blockIdx.x * 256 + threadIdx.x;
    if (e >= N_EDGES) return;
    int d = dst[e], r = et[e];
    int pos = atomicAdd(&cur2[d * 8 + r], 1);
    uint2 rc;
    rc.x = ((unsigned)src[e] << 3) | (unsigned)r;
    rc.y = __float_as_uint(norm[e]);
    recs[pos] = rc;
}

// ---------------------------------------------------------------------------
// K_mega (R10 shape + R11 B-path): 16 nodes/block, 256 thr (4 waves),
//  LDS 41,216 B -> 3 blocks/CU (latency overlap across blocks).
//  P1b gather: 16 groups x 1 node, (dst,et)-sorted runs -> reg acc, flush/et
//    (verbatim R10/R15 code). Tcat rows 0..15 incl self-loop slice.
//  P2 MFMA: wave wv owns col-tiles {wv, wv+4}; B = WcatF coalesced 1KB
//    fragment segments; ONE A-read (row=lrow) feeds both MFMAs per ks.
//  P3 MFMA with fwF, same decomposition. P4 LayerNorm (4 waves x 4 rows).
__global__ __launch_bounds__(256)
void k_mega(const bf16* __restrict__ hb16, const uint2* __restrict__ recs,
            const int* __restrict__ base, const bf16* __restrict__ WcatF,
            const float* __restrict__ bias,
            const bf16* __restrict__ fwF, const float* __restrict__ ffn_b,
            const float* __restrict__ ln_g, const float* __restrict__ ln_b,
            float* __restrict__ out) {
    __shared__ __align__(16) char Tf[TN * TROW];    // 37,120 B bf16 Tcat
    __shared__ __align__(16) char hnb[TN * 256];    // 4 KB bf16 swz
    char* aggy = Tf;                                // 8 KB alias for P3/P4
    const int t = threadIdx.x, wv = t >> 6, l = t & 63;
    const int n0 = blockIdx.x * TN;

    // ---- P0: zero relation region [0, 2048)B of each row ----
    {
        const f32x4 z4{0.f, 0.f, 0.f, 0.f};
#pragma unroll
        for (int u = t; u < TN * 128; u += 256) {
            int row = u >> 7, off = (u & 127) * 16;
            *(f32x4*)(Tf + row * TROW + off) = z4;
        }
    }
    __syncthreads();

    const int grp = t >> 4, c = t & 15;
    const int gbase = l & 48;            // group's base lane within wave
    const int n = n0 + grp;
    const long long nc = (n < N_NODES) ? n : (N_NODES - 1);
    const int rowb = grp * TROW;

    // ---- P1a: self-loop slice (bytes 2048..2304): direct bf16 copy ----
    *(bf16x8*)(Tf + rowb + 2048 + c * 16) =
        *(const bf16x8*)(hb16 + nc * DIM + c * 8);

    // ---- P1b: gather (sorted runs -> reg acc + flush per et) ----
    if (n < N_NODES) {
        const int b0 = base[n], b1 = base[n + 1];
        float acc[8];
#pragma unroll
        for (int q = 0; q < 8; ++q) acc[q] = 0.f;
        int cur_et = -1;

        auto flush = [&]() {
            frag_u o;
#pragma unroll
            for (int q = 0; q < 8; ++q) o.e[q] = __float2bfloat16(acc[q]);
            *(bf16x8*)(Tf + rowb + cur_et * 256 + c * 16) = o.v;
#pragma unroll
            for (int q = 0; q < 8; ++q) acc[q] = 0.f;
        };

        for (int eb = b0; eb < b1; eb += 4) {
            const int rem = b1 - eb;
            uint2 md = (c < 4 && c < rem) ? recs[eb + c] : uint2{0u, 0u};
            const unsigned sk0 = (unsigned)__shfl((int)md.x, gbase + 0);
            const unsigned sk1 = (unsigned)__shfl((int)md.x, gbase + 1);
            const unsigned sk2 = (unsigned)__shfl((int)md.x, gbase + 2);
            const unsigned sk3 = (unsigned)__shfl((int)md.x, gbase + 3);
            const float wk0 = __uint_as_float(__shfl((int)md.y, gbase + 0));
            const float wk1 = __uint_as_float(__shfl((int)md.y, gbase + 1));
            const float wk2 = __uint_as_float(__shfl((int)md.y, gbase + 2));
            const float wk3 = __uint_as_float(__shfl((int)md.y, gbase + 3));
            frag_u f0, f1, f2, f3;   // 4 independent L2 loads in flight
            f0.v = *(const bf16x8*)(hb16 + (long long)(sk0 >> 3) * DIM + c * 8);
            f1.v = *(const bf16x8*)(hb16 + (long long)(sk1 >> 3) * DIM + c * 8);
            f2.v = *(const bf16x8*)(hb16 + (long long)(sk2 >> 3) * DIM + c * 8);
            f3.v = *(const bf16x8*)(hb16 + (long long)(sk3 >> 3) * DIM + c * 8);

#define STEP(K, SK, WK, FK)                                              \
            if (K < rem) {                                               \
                const int et_ = (int)(SK & 7u);                          \
                if (et_ != cur_et) {                                     \
                    if (cur_et >= 0) flush();                            \
                    cur_et = et_;                                        \
                }                                                        \
                _Pragma("unroll")                                        \
                for (int q = 0; q < 8; ++q)                              \
                    acc[q] = fmaf(WK, __bfloat162float(FK.e[q]), acc[q]);\
            }
            STEP(0, sk0, wk0, f0)
            STEP(1, sk1, wk1, f1)
            STEP(2, sk2, wk2, f2)
            STEP(3, sk3, wk3, f3)
#undef STEP
        }
        if (cur_et >= 0) flush();
    }
    __syncthreads();

    // ---- P2: hn = relu(Tcat @ Wcat + bias), K=1152.
    //      Wave wv: col tiles ct0=wv, ct1=wv+4; rows 0..15 (row = lrow).
    //      One A-read per ks feeds both MFMAs. ----
    const int lrow = l & 15, kgrp = l >> 4;
    const int ct0 = wv, ct1 = wv + 4;
    {
        f32x4 acc1[2];
#pragma unroll
        for (int ci = 0; ci < 2; ++ci) acc1[ci] = f32x4{0.f, 0.f, 0.f, 0.f};
        const bf16* Bf0 = WcatF + (long long)ct0 * NKS * 512;
        const bf16* Bf1 = WcatF + (long long)ct1 * NKS * 512;
#pragma unroll 4
        for (int ks = 0; ks < NKS; ++ks) {
            frag_u b0, b1, a;
            b0.v = *(const bf16x8*)(Bf0 + ks * 512 + l * 8);  // coalesced 1KB
            b1.v = *(const bf16x8*)(Bf1 + ks * 512 + l * 8);  // coalesced 1KB
            a.v  = *(const bf16x8*)(Tf + lrow * TROW + ks * 64 + kgrp * 16);
            acc1[0] = __builtin_amdgcn_mfma_f32_16x16x32_bf16(
                b0.v, a.v, acc1[0], 0, 0, 0);
            acc1[1] = __builtin_amdgcn_mfma_f32_16x16x32_bf16(
                b1.v, a.v, acc1[1], 0, 0, 0);
        }
#pragma unroll
        for (int ci = 0; ci < 2; ++ci) {
            const int col = (wv + ci * 4) * 16 + kgrp * 4;
            f32x4 bi = *(const f32x4*)(bias + col);
            pack4_u p;
#pragma unroll
            for (int j = 0; j < 4; ++j)
                p.b[j] = __float2bfloat16(fmaxf(acc1[ci][j] + bi[j], 0.f));
            *(unsigned long long*)(hnb + ((lrow * 256 + col * 2) ^ swzb(lrow))) = p.ll;
        }
    }
    __syncthreads();

    // ---- P3: y = hn @ ffn_w^T + ffn_b + h, K=128 -> aggy (aliases Tf) ----
    {
        f32x4 acc2[2];
#pragma unroll
        for (int ci = 0; ci < 2; ++ci) acc2[ci] = f32x4{0.f, 0.f, 0.f, 0.f};
        const bf16* Bf0 = fwF + (long long)ct0 * 4 * 512;
        const bf16* Bf1 = fwF + (long long)ct1 * 4 * 512;
#pragma unroll
        for (int ks = 0; ks < 4; ++ks) {
            frag_u b0, b1, a;
            b0.v = *(const bf16x8*)(Bf0 + ks * 512 + l * 8);  // coalesced 1KB
            b1.v = *(const bf16x8*)(Bf1 + ks * 512 + l * 8);  // coalesced 1KB
            a.v  = *(const bf16x8*)(hnb +
                     ((lrow * 256 + ks * 64 + kgrp * 16) ^ swzb(lrow)));
            acc2[0] = __builtin_amdgcn_mfma_f32_16x16x32_bf16(
                b0.v, a.v, acc2[0], 0, 0, 0);
            acc2[1] = __builtin_amdgcn_mfma_f32_16x16x32_bf16(
                b1.v, a.v, acc2[1], 0, 0, 0);
        }
        const long long gr = (n0 + lrow < N_NODES) ? (n0 + lrow) : (N_NODES - 1);
#pragma unroll
        for (int ci = 0; ci < 2; ++ci) {
            const int col = (wv + ci * 4) * 16 + kgrp * 4;
            f32x4 fb = *(const f32x4*)(ffn_b + col);
            pack4_u hp;
            hp.ll = *(const unsigned long long*)(hb16 + gr * DIM + col);
            f32x4 y;
#pragma unroll
            for (int j = 0; j < 4; ++j)
                y[j] = acc2[ci][j] + fb[j] + __bfloat162float(hp.b[j]);
            *(f32x4*)(aggy + lrow * 512 + ((col * 4) ^ swzy(lrow))) = y;
        }
    }
    __syncthreads();

    // ---- P4: LayerNorm. 4 waves x 4 rows. Addr swizzled; col = PRE-swz 2l. ----
#pragma unroll 1
    for (int jr = 0; jr < 4; ++jr) {
        const int row = wv * 4 + jr;
        const int nn = n0 + row;
        const int x = swzy(row);
        float2 yv = *(const float2*)(aggy + row * 512 + ((l * 8) ^ x));
        const int col = l * 2;
        float s = yv.x + yv.y, s2 = yv.x * yv.x + yv.y * yv.y;
#pragma unroll
        for (int m = 1; m < 64; m <<= 1) {
            s  += __shfl_xor(s, m);
            s2 += __shfl_xor(s2, m);
        }
        if (nn < N_NODES) {
            float mu  = s * (1.f / DIM);
            float var = s2 * (1.f / DIM) - mu * mu;
            float inv = rsqrtf(var + 1e-8f);
            float2 gv = *(const float2*)(ln_g + col);
            float2 bv = *(const float2*)(ln_b + col);
            float2 o2{(yv.x - mu) * inv * gv.x + bv.x,
                      (yv.y - mu) * inv * gv.y + bv.y};
            *(float2*)(out + (long long)nn * DIM + col) = o2;
        }
    }
}

// ---------------------------------------------------------------------------
extern "C" void kernel_launch(void* const* d_in, const int* in_sizes, int n_in,
                              void* d_out, int out_size, void* d_ws, size_t ws_size,
                              hipStream_t stream) {
    const float* h      = (const float*)d_in[0];
    const float* V      = (const float*)d_in[1];
    const float* w_comp = (const float*)d_in[2];
    const float* loop_w = (const float*)d_in[3];
    const float* bias   = (const float*)d_in[4];
    const float* ffn_w  = (const float*)d_in[5];
    const float* ffn_b  = (const float*)d_in[6];
    const float* ln_g   = (const float*)d_in[7];
    const float* ln_b   = (const float*)d_in[8];
    const float* norm   = (const float*)d_in[9];
    const int*   src    = (const int*)d_in[10];
    const int*   dst    = (const int*)d_in[11];
    const int*   etype  = (const int*)d_in[12];
    float* out = (float*)d_out;

    if (ws_size < (size_t)WS_NEEDED) return;

    char* ws = (char*)d_ws;
    bf16*  hb16  = (bf16*)(ws + HB16_OFF);
    uint2* recs  = (uint2*)(ws + RECS_OFF);
    int*   hist2 = (int*)(ws + HIST_OFF);
    int*   cur2  = (int*)(ws + CUR2_OFF);
    int*   deg   = (int*)(ws + DEG_OFF);
    int*   base  = (int*)(ws + BASE_OFF);
    bf16*  WcatF = (bf16*)(ws + WCAT_OFF);
    bf16*  fwF   = (bf16*)(ws + FWF_OFF);

    hipMemsetAsync(hist2, 0, N_NODES * NREL * sizeof(int), stream);

    k_prep<<<dim3(3125), dim3(256), 0, stream>>>(
        h, V, w_comp, loop_w, ffn_w, dst, etype, hb16, WcatF, fwF, hist2);

    k_deg<<<dim3((N_NODES + 255) / 256), dim3(256), 0, stream>>>(hist2, deg);
    k_scan<<<dim3(1), dim3(1024), 0, stream>>>(deg, base);
    k_sub<<<dim3((N_NODES + 255) / 256), dim3(256), 0, stream>>>(hist2, base, cur2);
    k_scatter<<<dim3((N_EDGES + 255) / 256), dim3(256), 0, stream>>>(
        src, dst, etype, norm, cur2, recs);

    k_mega<<<dim3((N_NODES + TN - 1) / TN), dim3(256), 0, stream>>>(
        hb16, recs, base, WcatF, bias, fwF, ffn_b, ln_g, ln_b, out);
}

// Round 17
// 146.456 us; speedup vs baseline: 3.0700x; 1.0180x over previous
//
#include <hip/hip_runtime.h>
#include <hip/hip_bf16.h>

#define N_NODES 50000
#define N_EDGES 400000
#define DIM     128
#define NREL    8
#define NBASES  4
#define KCAT    1152            // 8*128 relation slices + 128 self-loop
#define NKS     36              // KCAT/32
#define TN      16              // nodes per mega-block (proven shape)
#define TROW    2320            // Tcat bf16 row stride bytes (145*16B, odd -> spread)

typedef __hip_bfloat16 bf16;

typedef __bf16 bf16x8 __attribute__((ext_vector_type(8)));
typedef float  f32x4  __attribute__((ext_vector_type(4)));

union frag_u { bf16x8 v; bf16 e[8]; };
union pack4_u { unsigned long long ll; bf16 b[4]; };

// ---- workspace layout (bytes) ----
// hb16  bf16 [N][D]          : 12,800,000
// recs  uint2 [E]            :  3,200,000  ((dst,et)-sorted; key=(src<<3)|et)
// hist2 int [N*8]            :  1,600,000
// cur2  int [N*8]            :  1,600,000
// deg   int [N] pad          :    200,064
// base  int [N+1] pad        :    200,064
// WcatF bf16 [8][36][64][8]  :    294,912  (fragment-ordered stacked weights)
// fwF   bf16 [8][4][64][8]   :     32,768  (fragment-ordered ffn_w)
#define HB16_OFF  0LL
#define RECS_OFF  12800000LL
#define HIST_OFF  16000000LL
#define CUR2_OFF  17600000LL
#define DEG_OFF   19200000LL
#define BASE_OFF  19400064LL
#define WCAT_OFF  19600128LL
#define FWF_OFF   19895040LL
#define WS_NEEDED 19927808LL

__device__ __forceinline__ int swzb(int row) { return (row & 15) << 4; }  // 256B rows
__device__ __forceinline__ int swzy(int row) { return (row & 31) << 4; }  // 512B rows

// ---------------------------------------------------------------------------
// K_prep: hb16 = bf16(h); hist2[(dst,et)]++; WcatF/fwF in FRAGMENT ORDER:
//   WcatF element (ct,ks,l,j) = Wcat^T[ct*16+(l&15)][ks*32+(l>>4)*8+j]
__global__ __launch_bounds__(256)
void k_prep(const float* __restrict__ h, const float* __restrict__ V,
            const float* __restrict__ wc,
            const float* __restrict__ loop_w, const float* __restrict__ ffn_w,
            const int* __restrict__ dst, const int* __restrict__ et,
            bf16* __restrict__ hb, bf16* __restrict__ WcatF,
            bf16* __restrict__ fwF, int* __restrict__ hist2) {
    int p = blockIdx.x * 256 + threadIdx.x;
    if (p < N_NODES * DIM / 8) {
        const float* s = h + (long long)p * 8;
        f32x4 lo = *(const f32x4*)s, hi = *(const f32x4*)(s + 4);
        frag_u o;
#pragma unroll
        for (int j = 0; j < 4; ++j) {
            o.e[j]     = __float2bfloat16(lo[j]);
            o.e[4 + j] = __float2bfloat16(hi[j]);
        }
        *(bf16x8*)(hb + (long long)p * 8) = o.v;
    }
    if (p < N_EDGES) atomicAdd(&hist2[dst[p] * 8 + et[p]], 1);
    if (p < 8 * NKS * 64 * 8) {            // 147456 WcatF elements
        int idx = p;
        int j = idx & 7; idx >>= 3;
        int l = idx & 63; idx >>= 6;
        int ks = idx % NKS, ct = idx / NKS;
        int col = ct * 16 + (l & 15);
        int k = ks * 32 + (l >> 4) * 8 + j;
        float val;
        if (k < 1024) {
            int r = k >> 7, i = k & 127;
            val = 0.f;
#pragma unroll
            for (int b = 0; b < NBASES; ++b)
                val += wc[r * NBASES + b] * V[(b << 14) + i * DIM + col];
        } else {
            val = loop_w[(k - 1024) * DIM + col];
        }
        WcatF[p] = __float2bfloat16(val);
    }
    if (p < 8 * 4 * 64 * 8) {              // 16384 fwF elements
        int idx = p;
        int j = idx & 7; idx >>= 3;
        int l = idx & 63; idx >>= 6;
        int ks = idx & 3, ct = idx >> 2;
        int col = ct * 16 + (l & 15);
        int k = ks * 32 + (l >> 4) * 8 + j;
        fwF[p] = __float2bfloat16(ffn_w[col * DIM + k]);   // ffn_w[o][i]
    }
}

// ---------------------------------------------------------------------------
// K_deg: deg[d] = sum_et hist2[d][et]
__global__ __launch_bounds__(256)
void k_deg(const int* __restrict__ hist2, int* __restrict__ deg) {
    int d = blockIdx.x * 256 + threadIdx.x;
    if (d < N_NODES) {
        int4 a = *(const int4*)(hist2 + d * 8);
        int4 b = *(const int4*)(hist2 + d * 8 + 4);
        deg[d] = a.x + a.y + a.z + a.w + b.x + b.y + b.z + b.w;
    }
}

// ---------------------------------------------------------------------------
// K_scan: exclusive prefix sum of deg -> base. 1 block, 1024 thr.
#define SCAN_V 13
__global__ __launch_bounds__(1024)
void k_scan(const int* __restrict__ deg, int* __restrict__ base) {
    __shared__ int wsum[16];
    const int t = threadIdx.x, lane = t & 63, wv = t >> 6;
    const int i0 = t * (SCAN_V * 4);
    int4 v[SCAN_V];
#pragma unroll
    for (int i = 0; i < SCAN_V; ++i) {
        int idx = i0 + i * 4;
        if (idx + 3 < N_NODES) v[i] = *(const int4*)(deg + idx);
        else {
            v[i].x = (idx + 0 < N_NODES) ? deg[idx + 0] : 0;
            v[i].y = (idx + 1 < N_NODES) ? deg[idx + 1] : 0;
            v[i].z = (idx + 2 < N_NODES) ? deg[idx + 2] : 0;
            v[i].w = (idx + 3 < N_NODES) ? deg[idx + 3] : 0;
        }
    }
    int s = 0;
#pragma unroll
    for (int i = 0; i < SCAN_V; ++i) s += v[i].x + v[i].y + v[i].z + v[i].w;
    int inc = s;
#pragma unroll
    for (int m = 1; m < 64; m <<= 1) {
        int u = __shfl_up(inc, m);
        if (lane >= m) inc += u;
    }
    if (lane == 63) wsum[wv] = inc;
    __syncthreads();
    if (t < 16) {
        int w = wsum[t];
        int winc = w;
#pragma unroll
        for (int m = 1; m < 16; m <<= 1) {
            int u = __shfl_up(winc, m);
            if (t >= m) winc += u;
        }
        wsum[t] = winc - w;
    }
    __syncthreads();
    int run = wsum[wv] + (inc - s);
#pragma unroll
    for (int i = 0; i < SCAN_V; ++i) {
        int idx = i0 + i * 4;
        if (idx + 3 < N_NODES) {
            int4 o;
            o.x = run; o.y = o.x + v[i].x; o.z = o.y + v[i].y; o.w = o.z + v[i].z;
            run = o.w + v[i].w;
            *(int4*)(base + idx) = o;
        } else {
            if (idx + 0 < N_NODES) { base[idx+0] = run; run += v[i].x; }
            if (idx + 1 < N_NODES) { base[idx+1] = run; run += v[i].y; }
            if (idx + 2 < N_NODES) { base[idx+2] = run; run += v[i].z; }
            if (idx + 3 < N_NODES) { base[idx+3] = run; run += v[i].w; }
        }
    }
    if (t == 1023) base[N_NODES] = run;
}

// ---------------------------------------------------------------------------
// K_sub: cur2[d][et] = base[d] + exclusive-prefix_et(hist2[d][.])
__global__ __launch_bounds__(256)
void k_sub(const int* __restrict__ hist2, const int* __restrict__ base,
           int* __restrict__ cur2) {
    int d = blockIdx.x * 256 + threadIdx.x;
    if (d < N_NODES) {
        int4 a = *(const int4*)(hist2 + d * 8);
        int4 b = *(const int4*)(hist2 + d * 8 + 4);
        int run = base[d];
        int4 oa, ob;
        oa.x = run; run += a.x;
        oa.y = run; run += a.y;
        oa.z = run; run += a.z;
        oa.w = run; run += a.w;
        ob.x = run; run += b.x;
        ob.y = run; run += b.y;
        ob.z = run; run += b.z;
        ob.w = run;
        *(int4*)(cur2 + d * 8)     = oa;
        *(int4*)(cur2 + d * 8 + 4) = ob;
    }
}

// ---------------------------------------------------------------------------
// K_scatter: bucket edges by (dst, et). recs = {(src<<3)|et, bits(norm)}.
__global__ __launch_bounds__(256)
void k_scatter(const int* __restrict__ src, const int* __restrict__ dst,
               const int* __restrict__ et, const float* __restrict__ norm,
               int* __restrict__ cur2, uint2* __restrict__ recs) {
    int e = blockIdx.x * 256 + threadIdx.x;
    if (e >= N_EDGES) return;
    int d = dst[e], r = et[e];
    int pos = atomicAdd(&cur2[d * 8 + r], 1);
    uint2 rc;
    rc.x = ((unsigned)src[e] << 3) | (unsigned)r;
    rc.y = __float_as_uint(norm[e]);
    recs[pos] = rc;
}

// ---------------------------------------------------------------------------
// K_mega: 16 nodes/block, 256 thr (4 waves), LDS 41,216 B -> 3 blocks/CU.
//  P1b gather: 16 groups x 1 node, (dst,et)-sorted runs -> reg acc, flush/et.
//    8-EDGE UNROLL: metadata from lanes c<8, 8 shuffled keys -> 8 INDEPENDENT
//    row loads in flight per group (deg<=8 node = ONE iteration).
//  P2 MFMA: wave wv owns col-tiles {wv, wv+4}; B = WcatF coalesced 1KB
//    fragment segments; ONE A-read (row=lrow) feeds both MFMAs per ks.
//  P3 MFMA with fwF, same decomposition. P4 LayerNorm (4 waves x 4 rows).
__global__ __launch_bounds__(256)
void k_mega(const bf16* __restrict__ hb16, const uint2* __restrict__ recs,
            const int* __restrict__ base, const bf16* __restrict__ WcatF,
            const float* __restrict__ bias,
            const bf16* __restrict__ fwF, const float* __restrict__ ffn_b,
            const float* __restrict__ ln_g, const float* __restrict__ ln_b,
            float* __restrict__ out) {
    __shared__ __align__(16) char Tf[TN * TROW];    // 37,120 B bf16 Tcat
    __shared__ __align__(16) char hnb[TN * 256];    // 4 KB bf16 swz
    char* aggy = Tf;                                // 8 KB alias for P3/P4
    const int t = threadIdx.x, wv = t >> 6, l = t & 63;
    const int n0 = blockIdx.x * TN;

    // ---- P0: zero relation region [0, 2048)B of each row ----
    {
        const f32x4 z4{0.f, 0.f, 0.f, 0.f};
#pragma unroll
        for (int u = t; u < TN * 128; u += 256) {
            int row = u >> 7, off = (u & 127) * 16;
            *(f32x4*)(Tf + row * TROW + off) = z4;
        }
    }
    __syncthreads();

    const int grp = t >> 4, c = t & 15;
    const int gbase = l & 48;            // group's base lane within wave
    const int n = n0 + grp;
    const long long nc = (n < N_NODES) ? n : (N_NODES - 1);
    const int rowb = grp * TROW;

    // ---- P1a: self-loop slice (bytes 2048..2304): direct bf16 copy ----
    *(bf16x8*)(Tf + rowb + 2048 + c * 16) =
        *(const bf16x8*)(hb16 + nc * DIM + c * 8);

    // ---- P1b: gather (sorted runs -> reg acc + flush per et), 8-edge unroll ----
    if (n < N_NODES) {
        const int b0 = base[n], b1 = base[n + 1];
        float acc[8];
#pragma unroll
        for (int q = 0; q < 8; ++q) acc[q] = 0.f;
        int cur_et = -1;

        auto flush = [&]() {
            frag_u o;
#pragma unroll
            for (int q = 0; q < 8; ++q) o.e[q] = __float2bfloat16(acc[q]);
            *(bf16x8*)(Tf + rowb + cur_et * 256 + c * 16) = o.v;
#pragma unroll
            for (int q = 0; q < 8; ++q) acc[q] = 0.f;
        };

        for (int eb = b0; eb < b1; eb += 8) {
            const int rem = b1 - eb;
            uint2 md = (c < 8 && c < rem) ? recs[eb + c] : uint2{0u, 0u};
            const unsigned sk0 = (unsigned)__shfl((int)md.x, gbase + 0);
            const unsigned sk1 = (unsigned)__shfl((int)md.x, gbase + 1);
            const unsigned sk2 = (unsigned)__shfl((int)md.x, gbase + 2);
            const unsigned sk3 = (unsigned)__shfl((int)md.x, gbase + 3);
            const unsigned sk4 = (unsigned)__shfl((int)md.x, gbase + 4);
            const unsigned sk5 = (unsigned)__shfl((int)md.x, gbase + 5);
            const unsigned sk6 = (unsigned)__shfl((int)md.x, gbase + 6);
            const unsigned sk7 = (unsigned)__shfl((int)md.x, gbase + 7);
            const float wk0 = __uint_as_float(__shfl((int)md.y, gbase + 0));
            const float wk1 = __uint_as_float(__shfl((int)md.y, gbase + 1));
            const float wk2 = __uint_as_float(__shfl((int)md.y, gbase + 2));
            const float wk3 = __uint_as_float(__shfl((int)md.y, gbase + 3));
            const float wk4 = __uint_as_float(__shfl((int)md.y, gbase + 4));
            const float wk5 = __uint_as_float(__shfl((int)md.y, gbase + 5));
            const float wk6 = __uint_as_float(__shfl((int)md.y, gbase + 6));
            const float wk7 = __uint_as_float(__shfl((int)md.y, gbase + 7));
            frag_u f0, f1, f2, f3, f4, f5, f6, f7;  // 8 indep loads in flight
            f0.v = *(const bf16x8*)(hb16 + (long long)(sk0 >> 3) * DIM + c * 8);
            f1.v = *(const bf16x8*)(hb16 + (long long)(sk1 >> 3) * DIM + c * 8);
            f2.v = *(const bf16x8*)(hb16 + (long long)(sk2 >> 3) * DIM + c * 8);
            f3.v = *(const bf16x8*)(hb16 + (long long)(sk3 >> 3) * DIM + c * 8);
            f4.v = *(const bf16x8*)(hb16 + (long long)(sk4 >> 3) * DIM + c * 8);
            f5.v = *(const bf16x8*)(hb16 + (long long)(sk5 >> 3) * DIM + c * 8);
            f6.v = *(const bf16x8*)(hb16 + (long long)(sk6 >> 3) * DIM + c * 8);
            f7.v = *(const bf16x8*)(hb16 + (long long)(sk7 >> 3) * DIM + c * 8);

#define STEP(K, SK, WK, FK)                                              \
            if (K < rem) {                                               \
                const int et_ = (int)(SK & 7u);                          \
                if (et_ != cur_et) {                                     \
                    if (cur_et >= 0) flush();                            \
                    cur_et = et_;                                        \
                }                                                        \
                _Pragma("unroll")                                        \
                for (int q = 0; q < 8; ++q)                              \
                    acc[q] = fmaf(WK, __bfloat162float(FK.e[q]), acc[q]);\
            }
            STEP(0, sk0, wk0, f0)
            STEP(1, sk1, wk1, f1)
            STEP(2, sk2, wk2, f2)
            STEP(3, sk3, wk3, f3)
            STEP(4, sk4, wk4, f4)
            STEP(5, sk5, wk5, f5)
            STEP(6, sk6, wk6, f6)
            STEP(7, sk7, wk7, f7)
#undef STEP
        }
        if (cur_et >= 0) flush();
    }
    __syncthreads();

    // ---- P2: hn = relu(Tcat @ Wcat + bias), K=1152.
    //      Wave wv: col tiles ct0=wv, ct1=wv+4; rows 0..15 (row = lrow).
    //      One A-read per ks feeds both MFMAs. ----
    const int lrow = l & 15, kgrp = l >> 4;
    const int ct0 = wv, ct1 = wv + 4;
    {
        f32x4 acc1[2];
#pragma unroll
        for (int ci = 0; ci < 2; ++ci) acc1[ci] = f32x4{0.f, 0.f, 0.f, 0.f};
        const bf16* Bf0 = WcatF + (long long)ct0 * NKS * 512;
        const bf16* Bf1 = WcatF + (long long)ct1 * NKS * 512;
#pragma unroll 4
        for (int ks = 0; ks < NKS; ++ks) {
            frag_u b0, b1, a;
            b0.v = *(const bf16x8*)(Bf0 + ks * 512 + l * 8);  // coalesced 1KB
            b1.v = *(const bf16x8*)(Bf1 + ks * 512 + l * 8);  // coalesced 1KB
            a.v  = *(const bf16x8*)(Tf + lrow * TROW + ks * 64 + kgrp * 16);
            acc1[0] = __builtin_amdgcn_mfma_f32_16x16x32_bf16(
                b0.v, a.v, acc1[0], 0, 0, 0);
            acc1[1] = __builtin_amdgcn_mfma_f32_16x16x32_bf16(
                b1.v, a.v, acc1[1], 0, 0, 0);
        }
#pragma unroll
        for (int ci = 0; ci < 2; ++ci) {
            const int col = (wv + ci * 4) * 16 + kgrp * 4;
            f32x4 bi = *(const f32x4*)(bias + col);
            pack4_u p;
#pragma unroll
            for (int j = 0; j < 4; ++j)
                p.b[j] = __float2bfloat16(fmaxf(acc1[ci][j] + bi[j], 0.f));
            *(unsigned long long*)(hnb + ((lrow * 256 + col * 2) ^ swzb(lrow))) = p.ll;
        }
    }
    __syncthreads();

    // ---- P3: y = hn @ ffn_w^T + ffn_b + h, K=128 -> aggy (aliases Tf) ----
    {
        f32x4 acc2[2];
#pragma unroll
        for (int ci = 0; ci < 2; ++ci) acc2[ci] = f32x4{0.f, 0.f, 0.f, 0.f};
        const bf16* Bf0 = fwF + (long long)ct0 * 4 * 512;
        const bf16* Bf1 = fwF + (long long)ct1 * 4 * 512;
#pragma unroll
        for (int ks = 0; ks < 4; ++ks) {
            frag_u b0, b1, a;
            b0.v = *(const bf16x8*)(Bf0 + ks * 512 + l * 8);  // coalesced 1KB
            b1.v = *(const bf16x8*)(Bf1 + ks * 512 + l * 8);  // coalesced 1KB
            a.v  = *(const bf16x8*)(hnb +
                     ((lrow * 256 + ks * 64 + kgrp * 16) ^ swzb(lrow)));
            acc2[0] = __builtin_amdgcn_mfma_f32_16x16x32_bf16(
                b0.v, a.v, acc2[0], 0, 0, 0);
            acc2[1] = __builtin_amdgcn_mfma_f32_16x16x32_bf16(
                b1.v, a.v, acc2[1], 0, 0, 0);
        }
        const long long gr = (n0 + lrow < N_NODES) ? (n0 + lrow) : (N_NODES - 1);
#pragma unroll
        for (int ci = 0; ci < 2; ++ci) {
            const int col = (wv + ci * 4) * 16 + kgrp * 4;
            f32x4 fb = *(const f32x4*)(ffn_b + col);
            pack4_u hp;
            hp.ll = *(const unsigned long long*)(hb16 + gr * DIM + col);
            f32x4 y;
#pragma unroll
            for (int j = 0; j < 4; ++j)
                y[j] = acc2[ci][j] + fb[j] + __bfloat162float(hp.b[j]);
            *(f32x4*)(aggy + lrow * 512 + ((col * 4) ^ swzy(lrow))) = y;
        }
    }
    __syncthreads();

    // ---- P4: LayerNorm. 4 waves x 4 rows. Addr swizzled; col = PRE-swz 2l. ----
#pragma unroll 1
    for (int jr = 0; jr < 4; ++jr) {
        const int row = wv * 4 + jr;
        const int nn = n0 + row;
        const int x = swzy(row);
        float2 yv = *(const float2*)(aggy + row * 512 + ((l * 8) ^ x));
        const int col = l * 2;
        float s = yv.x + yv.y, s2 = yv.x * yv.x + yv.y * yv.y;
#pragma unroll
        for (int m = 1; m < 64; m <<= 1) {
            s  += __shfl_xor(s, m);
            s2 += __shfl_xor(s2, m);
        }
        if (nn < N_NODES) {
            float mu  = s * (1.f / DIM);
            float var = s2 * (1.f / DIM) - mu * mu;
            float inv = rsqrtf(var + 1e-8f);
            float2 gv = *(const float2*)(ln_g + col);
            float2 bv = *(const float2*)(ln_b + col);
            float2 o2{(yv.x - mu) * inv * gv.x + bv.x,
                      (yv.y - mu) * inv * gv.y + bv.y};
            *(float2*)(out + (long long)nn * DIM + col) = o2;
        }
    }
}

// ---------------------------------------------------------------------------
extern "C" void kernel_launch(void* const* d_in, const int* in_sizes, int n_in,
                              void* d_out, int out_size, void* d_ws, size_t ws_size,
                              hipStream_t stream) {
    const float* h      = (const float*)d_in[0];
    const float* V      = (const float*)d_in[1];
    const float* w_comp = (const float*)d_in[2];
    const float* loop_w = (const float*)d_in[3];
    const float* bias   = (const float*)d_in[4];
    const float* ffn_w  = (const float*)d_in[5];
    const float* ffn_b  = (const float*)d_in[6];
    const float* ln_g   = (const float*)d_in[7];
    const float* ln_b   = (const float*)d_in[8];
    const float* norm   = (const float*)d_in[9];
    const int*   src    = (const int*)d_in[10];
    const int*   dst    = (const int*)d_in[11];
    const int*   etype  = (const int*)d_in[12];
    float* out = (float*)d_out;

    if (ws_size < (size_t)WS_NEEDED) return;

    char* ws = (char*)d_ws;
    bf16*  hb16  = (bf16*)(ws + HB16_OFF);
    uint2* recs  = (uint2*)(ws + RECS_OFF);
    int*   hist2 = (int*)(ws + HIST_OFF);
    int*   cur2  = (int*)(ws + CUR2_OFF);
    int*   deg   = (int*)(ws + DEG_OFF);
    int*   base  = (int*)(ws + BASE_OFF);
    bf16*  WcatF = (bf16*)(ws + WCAT_OFF);
    bf16*  fwF   = (bf16*)(ws + FWF_OFF);

    hipMemsetAsync(hist2, 0, N_NODES * NREL * sizeof(int), stream);

    k_prep<<<dim3(3125), dim3(256), 0, stream>>>(
        h, V, w_comp, loop_w, ffn_w, dst, etype, hb16, WcatF, fwF, hist2);

    k_deg<<<dim3((N_NODES + 255) / 256), dim3(256), 0, stream>>>(hist2, deg);
    k_scan<<<dim3(1), dim3(1024), 0, stream>>>(deg, base);
    k_sub<<<dim3((N_NODES + 255) / 256), dim3(256), 0, stream>>>(hist2, base, cur2);
    k_scatter<<<dim3((N_EDGES + 255) / 256), dim3(256), 0, stream>>>(
        src, dst, etype, norm, cur2, recs);

    k_mega<<<dim3((N_NODES + TN - 1) / TN), dim3(256), 0, stream>>>(
        hb16, recs, base, WcatF, bias, fwF, ffn_b, ln_g, ln_b, out);
}

// Round 18
// 138.256 us; speedup vs baseline: 3.2521x; 1.0593x over previous
//
#include <hip/hip_runtime.h>
#include <hip/hip_bf16.h>

#define N_NODES 50000
#define N_EDGES 400000
#define DIM     128
#define NREL    8
#define NBASES  4
#define KCAT    1152            // 8*128 relation slices + 128 self-loop
#define NKS     36              // KCAT/32
#define TN      16              // nodes per mega-block (proven shape)
#define TROW    2304            // Tcat bf16 row stride bytes; XOR swizzle fixes banks

typedef __hip_bfloat16 bf16;

typedef __bf16 bf16x8 __attribute__((ext_vector_type(8)));
typedef float  f32x4  __attribute__((ext_vector_type(4)));

union frag_u { bf16x8 v; bf16 e[8]; };
union pack4_u { unsigned long long ll; bf16 b[4]; };

// ---- workspace layout (bytes) ----
// hb16  bf16 [N][D]          : 12,800,000
// recs  uint2 [E]            :  3,200,000  ((dst,et)-sorted; key=(src<<3)|et)
// hist2 int [N*8]            :  1,600,000
// cur2  int [N*8]            :  1,600,000
// deg   int [N] pad          :    200,064
// base  int [N+1] pad        :    200,064
// WcatF bf16 [8][36][64][8]  :    294,912  (fragment-ordered stacked weights)
// fwF   bf16 [8][4][64][8]   :     32,768  (fragment-ordered ffn_w)
#define HB16_OFF  0LL
#define RECS_OFF  12800000LL
#define HIST_OFF  16000000LL
#define CUR2_OFF  17600000LL
#define DEG_OFF   19200000LL
#define BASE_OFF  19400064LL
#define WCAT_OFF  19600128LL
#define FWF_OFF   19895040LL
#define WS_NEEDED 19927808LL

__device__ __forceinline__ int swzb(int row) { return (row & 15) << 4; }  // 256B rows
__device__ __forceinline__ int swzy(int row) { return (row & 31) << 4; }  // 512B rows
__device__ __forceinline__ int swzt(int row) { return (row & 7) << 4; }   // Tcat rows (stride 2304)

// ---------------------------------------------------------------------------
// K_prep: hb16 = bf16(h); hist2[(dst,et)]++; WcatF/fwF in FRAGMENT ORDER:
//   WcatF element (ct,ks,l,j) = Wcat^T[ct*16+(l&15)][ks*32+(l>>4)*8+j]
__global__ __launch_bounds__(256)
void k_prep(const float* __restrict__ h, const float* __restrict__ V,
            const float* __restrict__ wc,
            const float* __restrict__ loop_w, const float* __restrict__ ffn_w,
            const int* __restrict__ dst, const int* __restrict__ et,
            bf16* __restrict__ hb, bf16* __restrict__ WcatF,
            bf16* __restrict__ fwF, int* __restrict__ hist2) {
    int p = blockIdx.x * 256 + threadIdx.x;
    if (p < N_NODES * DIM / 8) {
        const float* s = h + (long long)p * 8;
        f32x4 lo = *(const f32x4*)s, hi = *(const f32x4*)(s + 4);
        frag_u o;
#pragma unroll
        for (int j = 0; j < 4; ++j) {
            o.e[j]     = __float2bfloat16(lo[j]);
            o.e[4 + j] = __float2bfloat16(hi[j]);
        }
        *(bf16x8*)(hb + (long long)p * 8) = o.v;
    }
    if (p < N_EDGES) atomicAdd(&hist2[dst[p] * 8 + et[p]], 1);
    if (p < 8 * NKS * 64 * 8) {            // 147456 WcatF elements
        int idx = p;
        int j = idx & 7; idx >>= 3;
        int l = idx & 63; idx >>= 6;
        int ks = idx % NKS, ct = idx / NKS;
        int col = ct * 16 + (l & 15);
        int k = ks * 32 + (l >> 4) * 8 + j;
        float val;
        if (k < 1024) {
            int r = k >> 7, i = k & 127;
            val = 0.f;
#pragma unroll
            for (int b = 0; b < NBASES; ++b)
                val += wc[r * NBASES + b] * V[(b << 14) + i * DIM + col];
        } else {
            val = loop_w[(k - 1024) * DIM + col];
        }
        WcatF[p] = __float2bfloat16(val);
    }
    if (p < 8 * 4 * 64 * 8) {              // 16384 fwF elements
        int idx = p;
        int j = idx & 7; idx >>= 3;
        int l = idx & 63; idx >>= 6;
        int ks = idx & 3, ct = idx >> 2;
        int col = ct * 16 + (l & 15);
        int k = ks * 32 + (l >> 4) * 8 + j;
        fwF[p] = __float2bfloat16(ffn_w[col * DIM + k]);   // ffn_w[o][i]
    }
}

// ---------------------------------------------------------------------------
// K_deg: deg[d] = sum_et hist2[d][et]
__global__ __launch_bounds__(256)
void k_deg(const int* __restrict__ hist2, int* __restrict__ deg) {
    int d = blockIdx.x * 256 + threadIdx.x;
    if (d < N_NODES) {
        int4 a = *(const int4*)(hist2 + d * 8);
        int4 b = *(const int4*)(hist2 + d * 8 + 4);
        deg[d] = a.x + a.y + a.z + a.w + b.x + b.y + b.z + b.w;
    }
}

// ---------------------------------------------------------------------------
// K_scan: exclusive prefix sum of deg -> base. 1 block, 1024 thr.
#define SCAN_V 13
__global__ __launch_bounds__(1024)
void k_scan(const int* __restrict__ deg, int* __restrict__ base) {
    __shared__ int wsum[16];
    const int t = threadIdx.x, lane = t & 63, wv = t >> 6;
    const int i0 = t * (SCAN_V * 4);
    int4 v[SCAN_V];
#pragma unroll
    for (int i = 0; i < SCAN_V; ++i) {
        int idx = i0 + i * 4;
        if (idx + 3 < N_NODES) v[i] = *(const int4*)(deg + idx);
        else {
            v[i].x = (idx + 0 < N_NODES) ? deg[idx + 0] : 0;
            v[i].y = (idx + 1 < N_NODES) ? deg[idx + 1] : 0;
            v[i].z = (idx + 2 < N_NODES) ? deg[idx + 2] : 0;
            v[i].w = (idx + 3 < N_NODES) ? deg[idx + 3] : 0;
        }
    }
    int s = 0;
#pragma unroll
    for (int i = 0; i < SCAN_V; ++i) s += v[i].x + v[i].y + v[i].z + v[i].w;
    int inc = s;
#pragma unroll
    for (int m = 1; m < 64; m <<= 1) {
        int u = __shfl_up(inc, m);
        if (lane >= m) inc += u;
    }
    if (lane == 63) wsum[wv] = inc;
    __syncthreads();
    if (t < 16) {
        int w = wsum[t];
        int winc = w;
#pragma unroll
        for (int m = 1; m < 16; m <<= 1) {
            int u = __shfl_up(winc, m);
            if (t >= m) winc += u;
        }
        wsum[t] = winc - w;
    }
    __syncthreads();
    int run = wsum[wv] + (inc - s);
#pragma unroll
    for (int i = 0; i < SCAN_V; ++i) {
        int idx = i0 + i * 4;
        if (idx + 3 < N_NODES) {
            int4 o;
            o.x = run; o.y = o.x + v[i].x; o.z = o.y + v[i].y; o.w = o.z + v[i].z;
            run = o.w + v[i].w;
            *(int4*)(base + idx) = o;
        } else {
            if (idx + 0 < N_NODES) { base[idx+0] = run; run += v[i].x; }
            if (idx + 1 < N_NODES) { base[idx+1] = run; run += v[i].y; }
            if (idx + 2 < N_NODES) { base[idx+2] = run; run += v[i].z; }
            if (idx + 3 < N_NODES) { base[idx+3] = run; run += v[i].w; }
        }
    }
    if (t == 1023) base[N_NODES] = run;
}

// ---------------------------------------------------------------------------
// K_sub: cur2[d][et] = base[d] + exclusive-prefix_et(hist2[d][.])
__global__ __launch_bounds__(256)
void k_sub(const int* __restrict__ hist2, const int* __restrict__ base,
           int* __restrict__ cur2) {
    int d = blockIdx.x * 256 + threadIdx.x;
    if (d < N_NODES) {
        int4 a = *(const int4*)(hist2 + d * 8);
        int4 b = *(const int4*)(hist2 + d * 8 + 4);
        int run = base[d];
        int4 oa, ob;
        oa.x = run; run += a.x;
        oa.y = run; run += a.y;
        oa.z = run; run += a.z;
        oa.w = run; run += a.w;
        ob.x = run; run += b.x;
        ob.y = run; run += b.y;
        ob.z = run; run += b.z;
        ob.w = run;
        *(int4*)(cur2 + d * 8)     = oa;
        *(int4*)(cur2 + d * 8 + 4) = ob;
    }
}

// ---------------------------------------------------------------------------
// K_scatter: bucket edges by (dst, et). recs = {(src<<3)|et, bits(norm)}.
__global__ __launch_bounds__(256)
void k_scatter(const int* __restrict__ src, const int* __restrict__ dst,
               const int* __restrict__ et, const float* __restrict__ norm,
               int* __restrict__ cur2, uint2* __restrict__ recs) {
    int e = blockIdx.x * 256 + threadIdx.x;
    if (e >= N_EDGES) return;
    int d = dst[e], r = et[e];
    int pos = atomicAdd(&cur2[d * 8 + r], 1);
    uint2 rc;
    rc.x = ((unsigned)src[e] << 3) | (unsigned)r;
    rc.y = __float_as_uint(norm[e]);
    recs[pos] = rc;
}

// ---------------------------------------------------------------------------
// K_mega: 16 nodes/block, 256 thr (4 waves), LDS 40,960 B EXACT -> 4 blocks/CU.
//  Tcat stride 2304 with XOR swizzle ((row&7)<<4) on in-row byte offset:
//  row bases are 128B-aligned, XOR spreads 16 A-read lanes across 8 slots
//  (2-way = free). Write/read sites use the SAME XOR (both-sides discipline).
//  P1b gather: 16 groups x 1 node, (dst,et)-sorted runs -> reg acc, flush/et
//    (8-edge unroll). P2: wave wv owns col-tiles {wv, wv+4}; B = WcatF
//    coalesced 1KB; one A-read feeds both MFMAs. P3 fwF. P4 LayerNorm.
__global__ __launch_bounds__(256)
void k_mega(const bf16* __restrict__ hb16, const uint2* __restrict__ recs,
            const int* __restrict__ base, const bf16* __restrict__ WcatF,
            const float* __restrict__ bias,
            const bf16* __restrict__ fwF, const float* __restrict__ ffn_b,
            const float* __restrict__ ln_g, const float* __restrict__ ln_b,
            float* __restrict__ out) {
    __shared__ __align__(16) char Tf[TN * TROW];    // 36,864 B bf16 Tcat
    __shared__ __align__(16) char hnb[TN * 256];    // 4 KB bf16 swz
    char* aggy = Tf;                                // 8 KB alias for P3/P4
    const int t = threadIdx.x, wv = t >> 6, l = t & 63;
    const int n0 = blockIdx.x * TN;

    // ---- P0: zero relation region [0, 2048)B of each row (XOR-invariant) ----
    {
        const f32x4 z4{0.f, 0.f, 0.f, 0.f};
#pragma unroll
        for (int u = t; u < TN * 128; u += 256) {
            int row = u >> 7, off = (u & 127) * 16;
            *(f32x4*)(Tf + row * TROW + off) = z4;
        }
    }
    __syncthreads();

    const int grp = t >> 4, c = t & 15;
    const int gbase = l & 48;            // group's base lane within wave
    const int n = n0 + grp;
    const long long nc = (n < N_NODES) ? n : (N_NODES - 1);
    const int rowb = grp * TROW;
    const int xt = swzt(grp);

    // ---- P1a: self-loop slice (in-row bytes 2048..2304, XOR'd) ----
    *(bf16x8*)(Tf + rowb + ((2048 + c * 16) ^ xt)) =
        *(const bf16x8*)(hb16 + nc * DIM + c * 8);

    // ---- P1b: gather (sorted runs -> reg acc + flush per et), 8-edge unroll ----
    if (n < N_NODES) {
        const int b0 = base[n], b1 = base[n + 1];
        float acc[8];
#pragma unroll
        for (int q = 0; q < 8; ++q) acc[q] = 0.f;
        int cur_et = -1;

        auto flush = [&]() {
            frag_u o;
#pragma unroll
            for (int q = 0; q < 8; ++q) o.e[q] = __float2bfloat16(acc[q]);
            *(bf16x8*)(Tf + rowb + ((cur_et * 256 + c * 16) ^ xt)) = o.v;
#pragma unroll
            for (int q = 0; q < 8; ++q) acc[q] = 0.f;
        };

        for (int eb = b0; eb < b1; eb += 8) {
            const int rem = b1 - eb;
            uint2 md = (c < 8 && c < rem) ? recs[eb + c] : uint2{0u, 0u};
            const unsigned sk0 = (unsigned)__shfl((int)md.x, gbase + 0);
            const unsigned sk1 = (unsigned)__shfl((int)md.x, gbase + 1);
            const unsigned sk2 = (unsigned)__shfl((int)md.x, gbase + 2);
            const unsigned sk3 = (unsigned)__shfl((int)md.x, gbase + 3);
            const unsigned sk4 = (unsigned)__shfl((int)md.x, gbase + 4);
            const unsigned sk5 = (unsigned)__shfl((int)md.x, gbase + 5);
            const unsigned sk6 = (unsigned)__shfl((int)md.x, gbase + 6);
            const unsigned sk7 = (unsigned)__shfl((int)md.x, gbase + 7);
            const float wk0 = __uint_as_float(__shfl((int)md.y, gbase + 0));
            const float wk1 = __uint_as_float(__shfl((int)md.y, gbase + 1));
            const float wk2 = __uint_as_float(__shfl((int)md.y, gbase + 2));
            const float wk3 = __uint_as_float(__shfl((int)md.y, gbase + 3));
            const float wk4 = __uint_as_float(__shfl((int)md.y, gbase + 4));
            const float wk5 = __uint_as_float(__shfl((int)md.y, gbase + 5));
            const float wk6 = __uint_as_float(__shfl((int)md.y, gbase + 6));
            const float wk7 = __uint_as_float(__shfl((int)md.y, gbase + 7));
            frag_u f0, f1, f2, f3, f4, f5, f6, f7;  // 8 indep loads in flight
            f0.v = *(const bf16x8*)(hb16 + (long long)(sk0 >> 3) * DIM + c * 8);
            f1.v = *(const bf16x8*)(hb16 + (long long)(sk1 >> 3) * DIM + c * 8);
            f2.v = *(const bf16x8*)(hb16 + (long long)(sk2 >> 3) * DIM + c * 8);
            f3.v = *(const bf16x8*)(hb16 + (long long)(sk3 >> 3) * DIM + c * 8);
            f4.v = *(const bf16x8*)(hb16 + (long long)(sk4 >> 3) * DIM + c * 8);
            f5.v = *(const bf16x8*)(hb16 + (long long)(sk5 >> 3) * DIM + c * 8);
            f6.v = *(const bf16x8*)(hb16 + (long long)(sk6 >> 3) * DIM + c * 8);
            f7.v = *(const bf16x8*)(hb16 + (long long)(sk7 >> 3) * DIM + c * 8);

#define STEP(K, SK, WK, FK)                                              \
            if (K < rem) {                                               \
                const int et_ = (int)(SK & 7u);                          \
                if (et_ != cur_et) {                                     \
                    if (cur_et >= 0) flush();                            \
                    cur_et = et_;                                        \
                }                                                        \
                _Pragma("unroll")                                        \
                for (int q = 0; q < 8; ++q)                              \
                    acc[q] = fmaf(WK, __bfloat162float(FK.e[q]), acc[q]);\
            }
            STEP(0, sk0, wk0, f0)
            STEP(1, sk1, wk1, f1)
            STEP(2, sk2, wk2, f2)
            STEP(3, sk3, wk3, f3)
            STEP(4, sk4, wk4, f4)
            STEP(5, sk5, wk5, f5)
            STEP(6, sk6, wk6, f6)
            STEP(7, sk7, wk7, f7)
#undef STEP
        }
        if (cur_et >= 0) flush();
    }
    __syncthreads();

    // ---- P2: hn = relu(Tcat @ Wcat + bias), K=1152.
    //      Wave wv: col tiles ct0=wv, ct1=wv+4; rows 0..15 (row = lrow).
    //      One A-read per ks feeds both MFMAs. A addr XOR'd with swzt(lrow). ----
    const int lrow = l & 15, kgrp = l >> 4;
    const int ct0 = wv, ct1 = wv + 4;
    const int xa = swzt(lrow);
    {
        f32x4 acc1[2];
#pragma unroll
        for (int ci = 0; ci < 2; ++ci) acc1[ci] = f32x4{0.f, 0.f, 0.f, 0.f};
        const bf16* Bf0 = WcatF + (long long)ct0 * NKS * 512;
        const bf16* Bf1 = WcatF + (long long)ct1 * NKS * 512;
#pragma unroll 4
        for (int ks = 0; ks < NKS; ++ks) {
            frag_u b0, b1, a;
            b0.v = *(const bf16x8*)(Bf0 + ks * 512 + l * 8);  // coalesced 1KB
            b1.v = *(const bf16x8*)(Bf1 + ks * 512 + l * 8);  // coalesced 1KB
            a.v  = *(const bf16x8*)(Tf + lrow * TROW +
                                    ((ks * 64 + kgrp * 16) ^ xa));
            acc1[0] = __builtin_amdgcn_mfma_f32_16x16x32_bf16(
                b0.v, a.v, acc1[0], 0, 0, 0);
            acc1[1] = __builtin_amdgcn_mfma_f32_16x16x32_bf16(
                b1.v, a.v, acc1[1], 0, 0, 0);
        }
#pragma unroll
        for (int ci = 0; ci < 2; ++ci) {
            const int col = (wv + ci * 4) * 16 + kgrp * 4;
            f32x4 bi = *(const f32x4*)(bias + col);
            pack4_u p;
#pragma unroll
            for (int j = 0; j < 4; ++j)
                p.b[j] = __float2bfloat16(fmaxf(acc1[ci][j] + bi[j], 0.f));
            *(unsigned long long*)(hnb + ((lrow * 256 + col * 2) ^ swzb(lrow))) = p.ll;
        }
    }
    __syncthreads();

    // ---- P3: y = hn @ ffn_w^T + ffn_b + h, K=128 -> aggy (aliases Tf) ----
    {
        f32x4 acc2[2];
#pragma unroll
        for (int ci = 0; ci < 2; ++ci) acc2[ci] = f32x4{0.f, 0.f, 0.f, 0.f};
        const bf16* Bf0 = fwF + (long long)ct0 * 4 * 512;
        const bf16* Bf1 = fwF + (long long)ct1 * 4 * 512;
#pragma unroll
        for (int ks = 0; ks < 4; ++ks) {
            frag_u b0, b1, a;
            b0.v = *(const bf16x8*)(Bf0 + ks * 512 + l * 8);  // coalesced 1KB
            b1.v = *(const bf16x8*)(Bf1 + ks * 512 + l * 8);  // coalesced 1KB
            a.v  = *(const bf16x8*)(hnb +
                     ((lrow * 256 + ks * 64 + kgrp * 16) ^ swzb(lrow)));
            acc2[0] = __builtin_amdgcn_mfma_f32_16x16x32_bf16(
                b0.v, a.v, acc2[0], 0, 0, 0);
            acc2[1] = __builtin_amdgcn_mfma_f32_16x16x32_bf16(
                b1.v, a.v, acc2[1], 0, 0, 0);
        }
        const long long gr = (n0 + lrow < N_NODES) ? (n0 + lrow) : (N_NODES - 1);
#pragma unroll
        for (int ci = 0; ci < 2; ++ci) {
            const int col = (wv + ci * 4) * 16 + kgrp * 4;
            f32x4 fb = *(const f32x4*)(ffn_b + col);
            pack4_u hp;
            hp.ll = *(const unsigned long long*)(hb16 + gr * DIM + col);
            f32x4 y;
#pragma unroll
            for (int j = 0; j < 4; ++j)
                y[j] = acc2[ci][j] + fb[j] + __bfloat162float(hp.b[j]);
            *(f32x4*)(aggy + lrow * 512 + ((col * 4) ^ swzy(lrow))) = y;
        }
    }
    __syncthreads();

    // ---- P4: LayerNorm. 4 waves x 4 rows. Addr swizzled; col = PRE-swz 2l. ----
#pragma unroll 1
    for (int jr = 0; jr < 4; ++jr) {
        const int row = wv * 4 + jr;
        const int nn = n0 + row;
        const int x = swzy(row);
        float2 yv = *(const float2*)(aggy + row * 512 + ((l * 8) ^ x));
        const int col = l * 2;
        float s = yv.x + yv.y, s2 = yv.x * yv.x + yv.y * yv.y;
#pragma unroll
        for (int m = 1; m < 64; m <<= 1) {
            s  += __shfl_xor(s, m);
            s2 += __shfl_xor(s2, m);
        }
        if (nn < N_NODES) {
            float mu  = s * (1.f / DIM);
            float var = s2 * (1.f / DIM) - mu * mu;
            float inv = rsqrtf(var + 1e-8f);
            float2 gv = *(const float2*)(ln_g + col);
            float2 bv = *(const float2*)(ln_b + col);
            float2 o2{(yv.x - mu) * inv * gv.x + bv.x,
                      (yv.y - mu) * inv * gv.y + bv.y};
            *(float2*)(out + (long long)nn * DIM + col) = o2;
        }
    }
}

// ---------------------------------------------------------------------------
extern "C" void kernel_launch(void* const* d_in, const int* in_sizes, int n_in,
                              void* d_out, int out_size, void* d_ws, size_t ws_size,
                              hipStream_t stream) {
    const float* h      = (const float*)d_in[0];
    const float* V      = (const float*)d_in[1];
    const float* w_comp = (const float*)d_in[2];
    const float* loop_w = (const float*)d_in[3];
    const float* bias   = (const float*)d_in[4];
    const float* ffn_w  = (const float*)d_in[5];
    const float* ffn_b  = (const float*)d_in[6];
    const float* ln_g   = (const float*)d_in[7];
    const float* ln_b   = (const float*)d_in[8];
    const float* norm   = (const float*)d_in[9];
    const int*   src    = (const int*)d_in[10];
    const int*   dst    = (const int*)d_in[11];
    const int*   etype  = (const int*)d_in[12];
    float* out = (float*)d_out;

    if (ws_size < (size_t)WS_NEEDED) return;

    char* ws = (char*)d_ws;
    bf16*  hb16  = (bf16*)(ws + HB16_OFF);
    uint2* recs  = (uint2*)(ws + RECS_OFF);
    int*   hist2 = (int*)(ws + HIST_OFF);
    int*   cur2  = (int*)(ws + CUR2_OFF);
    int*   deg   = (int*)(ws + DEG_OFF);
    int*   base  = (int*)(ws + BASE_OFF);
    bf16*  WcatF = (bf16*)(ws + WCAT_OFF);
    bf16*  fwF   = (bf16*)(ws + FWF_OFF);

    hipMemsetAsync(hist2, 0, N_NODES * NREL * sizeof(int), stream);

    k_prep<<<dim3(3125), dim3(256), 0, stream>>>(
        h, V, w_comp, loop_w, ffn_w, dst, etype, hb16, WcatF, fwF, hist2);

    k_deg<<<dim3((N_NODES + 255) / 256), dim3(256), 0, stream>>>(hist2, deg);
    k_scan<<<dim3(1), dim3(1024), 0, stream>>>(deg, base);
    k_sub<<<dim3((N_NODES + 255) / 256), dim3(256), 0, stream>>>(hist2, base, cur2);
    k_scatter<<<dim3((N_EDGES + 255) / 256), dim3(256), 0, stream>>>(
        src, dst, etype, norm, cur2, recs);

    k_mega<<<dim3((N_NODES + TN - 1) / TN), dim3(256), 0, stream>>>(
        hb16, recs, base, WcatF, bias, fwF, ffn_b, ln_g, ln_b, out);
}